// Round 1
// 187.984 us; speedup vs baseline: 1.0383x; 1.0383x over previous
//
#include <hip/hip_runtime.h>
#include <math.h>

#define Bv 4
#define Tv 1024
#define Dv 1024
#define Hv 16
#define DHv 64

typedef __attribute__((ext_vector_type(8))) short short8;
typedef __attribute__((ext_vector_type(4))) short short4v;
typedef __attribute__((ext_vector_type(4))) float f32x4;

#define MFMA16(a, b, c) __builtin_amdgcn_mfma_f32_16x16x32_bf16((a), (b), (c), 0, 0, 0)

__device__ __forceinline__ short f2bf(float f) {
    union { float f; unsigned u; } v; v.f = f;
    unsigned r = v.u + 0x7FFFu + ((v.u >> 16) & 1u);
    return (short)(r >> 16);
}

__device__ __forceinline__ void async16(const void* g, void* l) {
    __builtin_amdgcn_global_load_lds(
        (const __attribute__((address_space(1))) void*)g,
        (__attribute__((address_space(3))) void*)l, 16, 0, 0);
}

// Fragment read from a 64-short-wide tile stored with chunk-XOR swizzle
// (chunk cw of row r lives at slot cw ^ (r&7)). Used by the attention kernels.
__device__ __forceinline__ short8 frag64(const short* buf, int r, int cw) {
    return *(const short8*)&buf[r * 64 + ((cw ^ (r & 7)) << 3)];
}

// 32-short-wide (BK=32) variant: 4 chunks per row, slot = (cw ^ r) & 3.
__device__ __forceinline__ short8 frag32(const short* buf, int r, int cw) {
    return *(const short8*)&buf[r * 32 + (((cw ^ r) & 3) << 3)];
}

// ---------------- cast x -> bf16 ----------------
__global__ __launch_bounds__(256) void cast_x(const float* __restrict__ x, short* __restrict__ xb) {
    const int idx = blockIdx.x * 256 + threadIdx.x;
    float4 v = ((const float4*)x)[idx];
    short4v o;
    o[0] = f2bf(v.x); o[1] = f2bf(v.y); o[2] = f2bf(v.z); o[3] = f2bf(v.w);
    ((short4v*)xb)[idx] = o;
}

// ---------------- cast + transpose W -> Wt[n][k] bf16 ----------------
__global__ __launch_bounds__(256) void w_cast_t(
    const float* __restrict__ Wq, const float* __restrict__ Wk, const float* __restrict__ Wv,
    short* __restrict__ Wt)
{
    const float* W = (blockIdx.z == 0) ? Wq : (blockIdx.z == 1) ? Wk : Wv;
    short* Wto = Wt + (size_t)blockIdx.z * 1048576;
    __shared__ short Tl[64 * 72];
    const int k0 = blockIdx.y * 64, n0 = blockIdx.x * 64;
    const int tid = threadIdx.x;
    {
        const int r = tid >> 2, c16 = (tid & 3) * 16;
        const float* src = W + (size_t)(k0 + r) * Dv + n0 + c16;
        float4 f0 = ((const float4*)src)[0], f1 = ((const float4*)src)[1];
        float4 f2 = ((const float4*)src)[2], f3 = ((const float4*)src)[3];
        short8 s0, s1;
        s0[0] = f2bf(f0.x); s0[1] = f2bf(f0.y); s0[2] = f2bf(f0.z); s0[3] = f2bf(f0.w);
        s0[4] = f2bf(f1.x); s0[5] = f2bf(f1.y); s0[6] = f2bf(f1.z); s0[7] = f2bf(f1.w);
        s1[0] = f2bf(f2.x); s1[1] = f2bf(f2.y); s1[2] = f2bf(f2.z); s1[3] = f2bf(f2.w);
        s1[4] = f2bf(f3.x); s1[5] = f2bf(f3.y); s1[6] = f2bf(f3.z); s1[7] = f2bf(f3.w);
        *(short8*)&Tl[r * 72 + c16] = s0;
        *(short8*)&Tl[r * 72 + c16 + 8] = s1;
    }
    __syncthreads();
#pragma unroll
    for (int p = 0; p < 2; p++) {
        const int n = p * 32 + (tid >> 3), j8 = (tid & 7) * 8;
        short8 o;
#pragma unroll
        for (int jj = 0; jj < 8; jj++) o[jj] = Tl[(j8 + jj) * 72 + n];
        *(short8*)&Wto[(size_t)(n0 + n) * Dv + k0 + j8] = o;
    }
}

// ---------------- QKV projection: 256x256 tile, BK=32, 3-deep pipeline ----------------
// z=0: Q, natural layout out[token][feature].
// z=1,2: K,V written directly per-head transposed: dst[(b*16+h)][feature][tok&63].
// LDS (shorts): A slots @ {0, 8192, 16384}; B slots @ 24576 + {0, 8192, 16384}. 96 KiB total.
__device__ __forceinline__ void stage_tile(
    const short* __restrict__ xb, const short* __restrict__ Wt,
    const int* aOff, const int* bOff, const int* dOff,
    short* smem, int sl, int k)
{
#pragma unroll
    for (int p = 0; p < 2; p++) {
        async16(xb + aOff[p] + k, smem + sl + dOff[p]);
        async16(Wt + bOff[p] + k, smem + 24576 + sl + dOff[p]);
    }
}

__device__ __forceinline__ void compute_tile(
    const short* smem, int sl, int RM, int CN, int c, int q, f32x4 acc[8][4])
{
    const short* Ac = smem + sl;
    const short* Bc = smem + 24576 + sl;
    short8 bf[4], af[8];
#pragma unroll
    for (int j = 0; j < 4; j++) bf[j] = frag32(Bc, CN + j * 16 + c, q);
#pragma unroll
    for (int m = 0; m < 8; m++) af[m] = frag32(Ac, RM + m * 16 + c, q);
    __builtin_amdgcn_s_setprio(1);
#pragma unroll
    for (int m = 0; m < 8; m++)
#pragma unroll
        for (int j = 0; j < 4; j++)
            acc[m][j] = MFMA16(af[m], bf[j], acc[m][j]);
    __builtin_amdgcn_s_setprio(0);
}

__global__ __launch_bounds__(512, 2) void qkv_mfma(
    const short* __restrict__ xb, const short* __restrict__ Wt3,
    const float* __restrict__ bq, const float* __restrict__ bk, const float* __restrict__ bv,
    short* __restrict__ Qo, short* __restrict__ Kt, short* __restrict__ Vt)
{
    const int z = blockIdx.z;
    const short* Wt = Wt3 + (size_t)z * 1048576;
    const float* bias = (z == 0) ? bq : (z == 1) ? bk : bv;

    __shared__ short smem[49152];      // 96 KiB; reused as T[128][264] in the epilogue

    const int tid = threadIdx.x;
    const int lane = tid & 63, w = tid >> 6;
    const int q = lane >> 4, c = lane & 15;
    const int wr = w >> 2, wc = w & 3;
    const int RM = wr * 128, CN = wc * 64;
    const int bm = blockIdx.y * 256, bn = blockIdx.x * 256;

    // staging offsets (int: all < 2^23)
    int aOff[2], bOff[2], dOff[2];
#pragma unroll
    for (int p = 0; p < 2; p++) {
        const int idx = p * 512 + tid;
        const int r = idx >> 2, cs = idx & 3, cg = (cs ^ r) & 3;
        aOff[p] = (bm + r) * Dv + cg * 8;
        bOff[p] = (bn + r) * Dv + cg * 8;
        dOff[p] = idx * 8;
    }

    f32x4 acc[8][4] = {};

    // prologue: tile0 -> slot0, tile1 -> slot1 (issue order defines vmcnt retirement order)
    stage_tile(xb, Wt, aOff, bOff, dOff, smem, 0, 0);
    stage_tile(xb, Wt, aOff, bOff, dOff, smem, 8192, 32);

    int slC = 0, slS = 16384;
#pragma unroll 1
    for (int i = 0; i < 30; i++) {
        asm volatile("s_waitcnt vmcnt(4)" ::: "memory");   // tile i resident; tile i+1 in flight
        __builtin_amdgcn_s_barrier();
        __builtin_amdgcn_sched_barrier(0);
        stage_tile(xb, Wt, aOff, bOff, dOff, smem, slS, (i + 2) * 32);
        compute_tile(smem, slC, RM, CN, c, q, acc);
        slC += 8192; if (slC == 24576) slC = 0;
        slS += 8192; if (slS == 24576) slS = 0;
    }
    // tile 30 (tile 31 still in flight)
    asm volatile("s_waitcnt vmcnt(4)" ::: "memory");
    __builtin_amdgcn_s_barrier();
    __builtin_amdgcn_sched_barrier(0);
    compute_tile(smem, slC, RM, CN, c, q, acc);
    slC += 8192; if (slC == 24576) slC = 0;
    // tile 31
    asm volatile("s_waitcnt vmcnt(0)" ::: "memory");
    __builtin_amdgcn_s_barrier();
    __builtin_amdgcn_sched_barrier(0);
    compute_tile(smem, slC, RM, CN, c, q, acc);

    if (z == 0) {
#pragma unroll
        for (int j = 0; j < 4; j++) {
            const int col = bn + CN + j * 16 + c;
            const float bb = bias[col];
#pragma unroll
            for (int m = 0; m < 8; m++) {
#pragma unroll
                for (int r = 0; r < 4; r++) {
                    const int row = bm + RM + m * 16 + q * 4 + r;
                    Qo[(size_t)row * Dv + col] = f2bf(acc[m][j][r] + bb);
                }
            }
        }
    } else {
        short* dst = (z == 1) ? Kt : Vt;
        short* T = smem;                   // T[n][m], n in [0,128), m in [0,256), stride 264
        const int hb = bm >> 6;            // first head-block covered by this tile (4 total)
#pragma unroll
        for (int nh = 0; nh < 2; nh++) {
            __syncthreads();
            if ((wc >> 1) == nh) {
#pragma unroll
                for (int j = 0; j < 4; j++) {
                    const int nl = (wc & 1) * 64 + j * 16 + c;
                    const float bb = bias[bn + nh * 128 + nl];
#pragma unroll
                    for (int m = 0; m < 8; m++) {
                        short4v pk;
#pragma unroll
                        for (int r = 0; r < 4; r++) pk[r] = f2bf(acc[m][j][r] + bb);
                        *(short4v*)&T[nl * 264 + RM + m * 16 + q * 4] = pk;
                    }
                }
            }
            __syncthreads();
#pragma unroll
            for (int p = 0; p < 8; p++) {
                const int idx = p * 512 + tid;
                const int n = idx >> 5, k2 = idx & 31;
                short8 v = *(const short8*)&T[n * 264 + k2 * 8];
                const size_t addr = (size_t)(hb + (k2 >> 3)) * 65536 +
                                    (size_t)(bn + nh * 128 + n) * 64 + (k2 & 7) * 8;
                *(short8*)&dst[addr] = v;
            }
        }
    }
}

// ---------------- attention stats: row max m, 1/Z per (b,h,t) ----------------
__global__ __launch_bounds__(256) void attn_stats(
    const short* __restrict__ Kt, const short* __restrict__ Vt,
    const float* __restrict__ temp,
    float* __restrict__ mOut, float* __restrict__ zOut)
{
    const int b = blockIdx.z, h = blockIdx.y, t0 = blockIdx.x * 64;
    const int bh = b * Hv + h;
    const float ts = temp[h];
    __shared__ short Ks[64 * 64];
    __shared__ short Vs[128 * 64];
    const int tid = threadIdx.x;
    const int lane = tid & 63, w = tid >> 6;
    const int q = lane >> 4, c = lane & 15;
    const short* Kbase = Kt + (size_t)bh * 65536;
    const short* Vbase = Vt + (size_t)bh * 65536;

#pragma unroll
    for (int p = 0; p < 2; p++) {
        const int idx = p * 256 + tid;
        const int r = idx >> 3, cs = idx & 7, cg = cs ^ (r & 7);
        async16(Kbase + (size_t)(t0 + r) * 64 + cg * 8, Ks + idx * 8);
    }

    float m_run[4], z_run[4];
#pragma unroll
    for (int r = 0; r < 4; r++) { m_run[r] = -INFINITY; z_run[r] = 0.f; }

    short8 aK0, aK1;
    for (int s0 = 0; s0 < Tv; s0 += 128) {
        __syncthreads();
#pragma unroll
        for (int p = 0; p < 4; p++) {
            const int idx = p * 256 + tid;
            const int r = idx >> 3, cs = idx & 7, cg = cs ^ (r & 7);
            async16(Vbase + (size_t)(s0 + r) * 64 + cg * 8, Vs + idx * 8);
        }
        __syncthreads();
        if (s0 == 0) {
            aK0 = frag64(Ks, w * 16 + c, q);
            aK1 = frag64(Ks, w * 16 + c, 4 + q);
        }
        float lv[8][4];
#pragma unroll
        for (int sf = 0; sf < 8; sf++) {
            short8 b0 = frag64(Vs, sf * 16 + c, q);
            short8 b1 = frag64(Vs, sf * 16 + c, 4 + q);
            f32x4 l = {0.f, 0.f, 0.f, 0.f};
            l = MFMA16(aK0, b0, l);
            l = MFMA16(aK1, b1, l);
#pragma unroll
            for (int r = 0; r < 4; r++) lv[sf][r] = l[r] * ts;
        }
#pragma unroll
        for (int r = 0; r < 4; r++) {
            float vmax = lv[0][r];
#pragma unroll
            for (int sf = 1; sf < 8; sf++) vmax = fmaxf(vmax, lv[sf][r]);
            float mn = fmaxf(m_run[r], vmax);
            float za = 0.f;
#pragma unroll
            for (int sf = 0; sf < 8; sf++) za += __expf(lv[sf][r] - mn);
            z_run[r] = z_run[r] * __expf(m_run[r] - mn) + za;
            m_run[r] = mn;
        }
    }
#pragma unroll
    for (int mask = 1; mask <= 8; mask <<= 1) {
#pragma unroll
        for (int r = 0; r < 4; r++) {
            float om = __shfl_xor(m_run[r], mask, 64);
            float oz = __shfl_xor(z_run[r], mask, 64);
            float mn = fmaxf(m_run[r], om);
            z_run[r] = z_run[r] * __expf(m_run[r] - mn) + oz * __expf(om - mn);
            m_run[r] = mn;
        }
    }
    if (c == 0) {
#pragma unroll
        for (int r = 0; r < 4; r++) {
            const int t = t0 + w * 16 + q * 4 + r;
            mOut[(size_t)bh * Tv + t] = m_run[r];
            zOut[(size_t)bh * Tv + t] = 1.f / z_run[r];
        }
    }
}

// ---------------- attention output (s-tile = 128) ----------------
__global__ __launch_bounds__(256) void attn_out(
    const short* __restrict__ Qb, const short* __restrict__ Kt, const short* __restrict__ Vt,
    const float* __restrict__ temp, const float* __restrict__ mIn, const float* __restrict__ zIn,
    float* __restrict__ out)
{
    const int b = blockIdx.z, h = blockIdx.y, s0 = blockIdx.x * 128;
    const int bh = b * Hv + h;
    const float ts = temp[h];
    __shared__ short Vs[128 * 64];   // [s][j]
    __shared__ short Ks[64 * 64];    // [t][j]
    __shared__ short Qs[64 * 64];    // [dh][t]
    __shared__ short Pt[128 * 72];   // [s][t]
    __shared__ float ms[64], zs[64];
    const int tid = threadIdx.x;
    const int lane = tid & 63, w = tid >> 6;
    const int q = lane >> 4, c = lane & 15;
    const short* Vbase = Vt + (size_t)bh * 65536;
    const short* Kbase = Kt + (size_t)bh * 65536;
    const short* Qbase = Qb + (size_t)(b * Tv + h * DHv) * Dv;

#pragma unroll
    for (int p = 0; p < 4; p++) {
        const int idx = p * 256 + tid;
        const int r = idx >> 3, cs = idx & 7, cg = cs ^ (r & 7);
        async16(Vbase + (size_t)(s0 + r) * 64 + cg * 8, Vs + idx * 8);
    }

    f32x4 acc[8] = {};

    for (int t0 = 0; t0 < Tv; t0 += 64) {
        __syncthreads();
#pragma unroll
        for (int p = 0; p < 2; p++) {
            const int idx = p * 256 + tid;
            const int r = idx >> 3, cs = idx & 7, cg = cs ^ (r & 7);
            async16(Kbase + (size_t)(t0 + r) * 64 + cg * 8, Ks + idx * 8);
            async16(Qbase + (size_t)r * Dv + t0 + cg * 8, Qs + idx * 8);
        }
        if (tid < 64) {
            ms[tid] = mIn[(size_t)bh * Tv + t0 + tid];
            zs[tid] = zIn[(size_t)bh * Tv + t0 + tid];
        }
        __syncthreads();

        short8 aK0 = frag64(Ks, w * 16 + c, q);
        short8 aK1 = frag64(Ks, w * 16 + c, 4 + q);
#pragma unroll
        for (int sf = 0; sf < 8; sf++) {
            short8 b0 = frag64(Vs, sf * 16 + c, q);
            short8 b1 = frag64(Vs, sf * 16 + c, 4 + q);
            f32x4 l = {0.f, 0.f, 0.f, 0.f};
            l = MFMA16(aK0, b0, l);
            l = MFMA16(aK1, b1, l);
            short4v p4;
#pragma unroll
            for (int r = 0; r < 4; r++) {
                const int tr = w * 16 + q * 4 + r;
                float p = __expf(l[r] * ts - ms[tr]) * zs[tr];
                p4[r] = f2bf(p);
            }
            *(short4v*)&Pt[(sf * 16 + c) * 72 + w * 16 + q * 4] = p4;
        }
        __syncthreads();

        short8 aQ0 = frag64(Qs, w * 16 + c, q);
        short8 aQ1 = frag64(Qs, w * 16 + c, 4 + q);
#pragma unroll
        for (int sf = 0; sf < 8; sf++) {
            short8 p0 = *(const short8*)&Pt[(sf * 16 + c) * 72 + q * 8];
            short8 p1 = *(const short8*)&Pt[(sf * 16 + c) * 72 + 32 + q * 8];
            acc[sf] = MFMA16(aQ0, p0, acc[sf]);
            acc[sf] = MFMA16(aQ1, p1, acc[sf]);
        }
    }

#pragma unroll
    for (int sf = 0; sf < 8; sf++) {
#pragma unroll
        for (int r = 0; r < 4; r++) {
            const int d = w * 16 + q * 4 + r;
            out[(size_t)(b * Tv + h * DHv + d) * Dv + s0 + sf * 16 + c] = acc[sf][r];
        }
    }
}

extern "C" void kernel_launch(void* const* d_in, const int* in_sizes, int n_in,
                              void* d_out, int out_size, void* d_ws, size_t ws_size,
                              hipStream_t stream) {
    const float* x    = (const float*)d_in[0];
    const float* Wq   = (const float*)d_in[1];
    const float* bq   = (const float*)d_in[2];
    const float* Wk   = (const float*)d_in[3];
    const float* bk   = (const float*)d_in[4];
    const float* Wv   = (const float*)d_in[5];
    const float* bv   = (const float*)d_in[6];
    const float* temp = (const float*)d_in[7];
    float* out = (float*)d_out;

    char* ws = (char*)d_ws;
    short* xb = (short*)(ws);                       // [0, 8M)
    short* Wt = (short*)(ws + ((size_t)8 << 20));   // [8M, 14M)
    short* Qb = (short*)(ws + ((size_t)14 << 20));  // [14M, 22M)
    short* Kt = (short*)(ws + ((size_t)22 << 20));  // [22M, 30M)
    short* Vt = (short*)(ws + ((size_t)30 << 20));  // [30M, 38M)
    float* mbuf = (float*)(ws + ((size_t)38 << 20));
    float* zbuf = mbuf + 65536;

    cast_x<<<4096, 256, 0, stream>>>(x, xb);
    w_cast_t<<<dim3(16, 16, 3), 256, 0, stream>>>(Wq, Wk, Wv, Wt);
    qkv_mfma<<<dim3(4, 16, 3), 512, 0, stream>>>(xb, Wt, bq, bk, bv, Qb, Kt, Vt);
    attn_stats<<<dim3(16, 16, 4), 256, 0, stream>>>(Kt, Vt, temp, mbuf, zbuf);
    attn_out<<<dim3(8, 16, 4), 256, 0, stream>>>(Qb, Kt, Vt, temp, mbuf, zbuf, out);
}

// Round 2
// 176.889 us; speedup vs baseline: 1.1034x; 1.0627x over previous
//
#include <hip/hip_runtime.h>
#include <math.h>

#define Bv 4
#define Tv 1024
#define Dv 1024
#define Hv 16
#define DHv 64

typedef __attribute__((ext_vector_type(8))) short short8;
typedef __attribute__((ext_vector_type(4))) short short4v;
typedef __attribute__((ext_vector_type(4))) float f32x4;

#define MFMA16(a, b, c) __builtin_amdgcn_mfma_f32_16x16x32_bf16((a), (b), (c), 0, 0, 0)

__device__ __forceinline__ short f2bf(float f) {
    union { float f; unsigned u; } v; v.f = f;
    unsigned r = v.u + 0x7FFFu + ((v.u >> 16) & 1u);
    return (short)(r >> 16);
}

__device__ __forceinline__ void async16(const void* g, void* l) {
    __builtin_amdgcn_global_load_lds(
        (const __attribute__((address_space(1))) void*)g,
        (__attribute__((address_space(3))) void*)l, 16, 0, 0);
}

// Fragment read from a 64-short-wide tile stored with chunk-XOR swizzle
// (chunk cw of row r lives at slot cw ^ (r&7)). 2-way bank aliasing only.
__device__ __forceinline__ short8 frag64(const short* buf, int r, int cw) {
    return *(const short8*)&buf[r * 64 + ((cw ^ (r & 7)) << 3)];
}

// 32-short-wide (BK=32) variant: 4 chunks per row, slot = (cw ^ r) & 3.
__device__ __forceinline__ short8 frag32(const short* buf, int r, int cw) {
    return *(const short8*)&buf[r * 32 + (((cw ^ r) & 3) << 3)];
}

// lgkmcnt-only barrier: makes same-iteration LDS writes visible WITHOUT
// draining in-flight global_load_lds prefetches (vmcnt untouched).
__device__ __forceinline__ void lds_barrier() {
    asm volatile("s_waitcnt lgkmcnt(0)" ::: "memory");
    __builtin_amdgcn_sched_barrier(0);
    __builtin_amdgcn_s_barrier();
    __builtin_amdgcn_sched_barrier(0);
}

// ---------------- cast x -> bf16 ----------------
__global__ __launch_bounds__(256) void cast_x(const float* __restrict__ x, short* __restrict__ xb) {
    const int idx = blockIdx.x * 256 + threadIdx.x;
    float4 v = ((const float4*)x)[idx];
    short4v o;
    o[0] = f2bf(v.x); o[1] = f2bf(v.y); o[2] = f2bf(v.z); o[3] = f2bf(v.w);
    ((short4v*)xb)[idx] = o;
}

// ---------------- cast + transpose W -> Wt[n][k] bf16 ----------------
__global__ __launch_bounds__(256) void w_cast_t(
    const float* __restrict__ Wq, const float* __restrict__ Wk, const float* __restrict__ Wv,
    short* __restrict__ Wt)
{
    const float* W = (blockIdx.z == 0) ? Wq : (blockIdx.z == 1) ? Wk : Wv;
    short* Wto = Wt + (size_t)blockIdx.z * 1048576;
    __shared__ short Tl[64 * 72];
    const int k0 = blockIdx.y * 64, n0 = blockIdx.x * 64;
    const int tid = threadIdx.x;
    {
        const int r = tid >> 2, c16 = (tid & 3) * 16;
        const float* src = W + (size_t)(k0 + r) * Dv + n0 + c16;
        float4 f0 = ((const float4*)src)[0], f1 = ((const float4*)src)[1];
        float4 f2 = ((const float4*)src)[2], f3 = ((const float4*)src)[3];
        short8 s0, s1;
        s0[0] = f2bf(f0.x); s0[1] = f2bf(f0.y); s0[2] = f2bf(f0.z); s0[3] = f2bf(f0.w);
        s0[4] = f2bf(f1.x); s0[5] = f2bf(f1.y); s0[6] = f2bf(f1.z); s0[7] = f2bf(f1.w);
        s1[0] = f2bf(f2.x); s1[1] = f2bf(f2.y); s1[2] = f2bf(f2.z); s1[3] = f2bf(f2.w);
        s1[4] = f2bf(f3.x); s1[5] = f2bf(f3.y); s1[6] = f2bf(f3.z); s1[7] = f2bf(f3.w);
        *(short8*)&Tl[r * 72 + c16] = s0;
        *(short8*)&Tl[r * 72 + c16 + 8] = s1;
    }
    __syncthreads();
#pragma unroll
    for (int p = 0; p < 2; p++) {
        const int n = p * 32 + (tid >> 3), j8 = (tid & 7) * 8;
        short8 o;
#pragma unroll
        for (int jj = 0; jj < 8; jj++) o[jj] = Tl[(j8 + jj) * 72 + n];
        *(short8*)&Wto[(size_t)(n0 + n) * Dv + k0 + j8] = o;
    }
}

// ---------------- QKV projection: 256x256 tile, BK=32, 3-deep pipeline ----------------
__device__ __forceinline__ void stage_tile(
    const short* __restrict__ xb, const short* __restrict__ Wt,
    const int* aOff, const int* bOff, const int* dOff,
    short* smem, int sl, int k)
{
#pragma unroll
    for (int p = 0; p < 2; p++) {
        async16(xb + aOff[p] + k, smem + sl + dOff[p]);
        async16(Wt + bOff[p] + k, smem + 24576 + sl + dOff[p]);
    }
}

__device__ __forceinline__ void compute_tile(
    const short* smem, int sl, int RM, int CN, int c, int q, f32x4 acc[8][4])
{
    const short* Ac = smem + sl;
    const short* Bc = smem + 24576 + sl;
    short8 bf[4], af[8];
#pragma unroll
    for (int j = 0; j < 4; j++) bf[j] = frag32(Bc, CN + j * 16 + c, q);
#pragma unroll
    for (int m = 0; m < 8; m++) af[m] = frag32(Ac, RM + m * 16 + c, q);
    __builtin_amdgcn_s_setprio(1);
#pragma unroll
    for (int m = 0; m < 8; m++)
#pragma unroll
        for (int j = 0; j < 4; j++)
            acc[m][j] = MFMA16(af[m], bf[j], acc[m][j]);
    __builtin_amdgcn_s_setprio(0);
}

__global__ __launch_bounds__(512, 2) void qkv_mfma(
    const short* __restrict__ xb, const short* __restrict__ Wt3,
    const float* __restrict__ bq, const float* __restrict__ bk, const float* __restrict__ bv,
    short* __restrict__ Qo, short* __restrict__ Kt, short* __restrict__ Vt)
{
    const int z = blockIdx.z;
    const short* Wt = Wt3 + (size_t)z * 1048576;
    const float* bias = (z == 0) ? bq : (z == 1) ? bk : bv;

    __shared__ short smem[49152];

    const int tid = threadIdx.x;
    const int lane = tid & 63, w = tid >> 6;
    const int q = lane >> 4, c = lane & 15;
    const int wr = w >> 2, wc = w & 3;
    const int RM = wr * 128, CN = wc * 64;
    const int bm = blockIdx.y * 256, bn = blockIdx.x * 256;

    int aOff[2], bOff[2], dOff[2];
#pragma unroll
    for (int p = 0; p < 2; p++) {
        const int idx = p * 512 + tid;
        const int r = idx >> 2, cs = idx & 3, cg = (cs ^ r) & 3;
        aOff[p] = (bm + r) * Dv + cg * 8;
        bOff[p] = (bn + r) * Dv + cg * 8;
        dOff[p] = idx * 8;
    }

    f32x4 acc[8][4] = {};

    stage_tile(xb, Wt, aOff, bOff, dOff, smem, 0, 0);
    stage_tile(xb, Wt, aOff, bOff, dOff, smem, 8192, 32);

    int slC = 0, slS = 16384;
#pragma unroll 1
    for (int i = 0; i < 30; i++) {
        asm volatile("s_waitcnt vmcnt(4)" ::: "memory");
        __builtin_amdgcn_s_barrier();
        __builtin_amdgcn_sched_barrier(0);
        stage_tile(xb, Wt, aOff, bOff, dOff, smem, slS, (i + 2) * 32);
        compute_tile(smem, slC, RM, CN, c, q, acc);
        slC += 8192; if (slC == 24576) slC = 0;
        slS += 8192; if (slS == 24576) slS = 0;
    }
    asm volatile("s_waitcnt vmcnt(4)" ::: "memory");
    __builtin_amdgcn_s_barrier();
    __builtin_amdgcn_sched_barrier(0);
    compute_tile(smem, slC, RM, CN, c, q, acc);
    slC += 8192; if (slC == 24576) slC = 0;
    asm volatile("s_waitcnt vmcnt(0)" ::: "memory");
    __builtin_amdgcn_s_barrier();
    __builtin_amdgcn_sched_barrier(0);
    compute_tile(smem, slC, RM, CN, c, q, acc);

    if (z == 0) {
#pragma unroll
        for (int j = 0; j < 4; j++) {
            const int col = bn + CN + j * 16 + c;
            const float bb = bias[col];
#pragma unroll
            for (int m = 0; m < 8; m++) {
#pragma unroll
                for (int r = 0; r < 4; r++) {
                    const int row = bm + RM + m * 16 + q * 4 + r;
                    Qo[(size_t)row * Dv + col] = f2bf(acc[m][j][r] + bb);
                }
            }
        }
    } else {
        short* dst = (z == 1) ? Kt : Vt;
        short* T = smem;
        const int hb = bm >> 6;
#pragma unroll
        for (int nh = 0; nh < 2; nh++) {
            __syncthreads();
            if ((wc >> 1) == nh) {
#pragma unroll
                for (int j = 0; j < 4; j++) {
                    const int nl = (wc & 1) * 64 + j * 16 + c;
                    const float bb = bias[bn + nh * 128 + nl];
#pragma unroll
                    for (int m = 0; m < 8; m++) {
                        short4v pk;
#pragma unroll
                        for (int r = 0; r < 4; r++) pk[r] = f2bf(acc[m][j][r] + bb);
                        *(short4v*)&T[nl * 264 + RM + m * 16 + q * 4] = pk;
                    }
                }
            }
            __syncthreads();
#pragma unroll
            for (int p = 0; p < 8; p++) {
                const int idx = p * 512 + tid;
                const int n = idx >> 5, k2 = idx & 31;
                short8 v = *(const short8*)&T[n * 264 + k2 * 8];
                const size_t addr = (size_t)(hb + (k2 >> 3)) * 65536 +
                                    (size_t)(bn + nh * 128 + n) * 64 + (k2 & 7) * 8;
                *(short8*)&dst[addr] = v;
            }
        }
    }
}

// ---------------- attention stats: pipelined V, XCD-swizzled ----------------
__global__ __launch_bounds__(256, 4) void attn_stats(
    const short* __restrict__ Kt, const short* __restrict__ Vt,
    const float* __restrict__ temp,
    float* __restrict__ mOut, float* __restrict__ zOut)
{
    // XCD remap: the 16 t-blocks of one (b,h) share V -> same id mod 8 (same XCD L2).
    const int L = blockIdx.x + 16 * (blockIdx.y + 16 * blockIdx.z);
    const int bh = (L & 7) + 8 * (L >> 7);
    const int t0 = ((L >> 3) & 15) * 64;
    const float ts = temp[bh & 15];
    __shared__ short Ks[64 * 64];
    __shared__ short Vs[2][128 * 64];
    const int tid = threadIdx.x;
    const int lane = tid & 63, w = tid >> 6;
    const int q = lane >> 4, c = lane & 15;
    const short* Kbase = Kt + (size_t)bh * 65536;
    const short* Vbase = Vt + (size_t)bh * 65536;

    int vOff[4], vDst[4];
#pragma unroll
    for (int p = 0; p < 4; p++) {
        const int idx = p * 256 + tid;
        const int r = idx >> 3, cs = idx & 7, cg = cs ^ (r & 7);
        vOff[p] = r * 64 + cg * 8;
        vDst[p] = idx * 8;
    }
#pragma unroll
    for (int p = 0; p < 2; p++) {
        const int idx = p * 256 + tid;
        const int r = idx >> 3, cs = idx & 7, cg = cs ^ (r & 7);
        async16(Kbase + (size_t)(t0 + r) * 64 + cg * 8, Ks + idx * 8);
    }
#pragma unroll
    for (int p = 0; p < 4; p++) async16(Vbase + vOff[p], &Vs[0][0] + vDst[p]);

    float m_run[4], z_run[4];
#pragma unroll
    for (int r = 0; r < 4; r++) { m_run[r] = -INFINITY; z_run[r] = 0.f; }

    short8 aK0, aK1;
#pragma unroll 1
    for (int i = 0; i < 8; i++) {
        __syncthreads();                       // V(i) resident everywhere
        if (i < 7) {                           // prefetch V(i+1); drains at NEXT iter top
            const short* src = Vbase + (i + 1) * 8192;
#pragma unroll
            for (int p = 0; p < 4; p++) async16(src + vOff[p], &Vs[(i + 1) & 1][0] + vDst[p]);
        }
        if (i == 0) {
            aK0 = frag64(Ks, w * 16 + c, q);
            aK1 = frag64(Ks, w * 16 + c, 4 + q);
        }
        const short* Vc = &Vs[i & 1][0];
        float lv[8][4];
        __builtin_amdgcn_s_setprio(1);
#pragma unroll
        for (int sf = 0; sf < 8; sf++) {
            short8 b0 = frag64(Vc, sf * 16 + c, q);
            short8 b1 = frag64(Vc, sf * 16 + c, 4 + q);
            f32x4 l = {0.f, 0.f, 0.f, 0.f};
            l = MFMA16(aK0, b0, l);
            l = MFMA16(aK1, b1, l);
#pragma unroll
            for (int r = 0; r < 4; r++) lv[sf][r] = l[r] * ts;
        }
        __builtin_amdgcn_s_setprio(0);
#pragma unroll
        for (int r = 0; r < 4; r++) {
            float vmax = lv[0][r];
#pragma unroll
            for (int sf = 1; sf < 8; sf++) vmax = fmaxf(vmax, lv[sf][r]);
            float mn = fmaxf(m_run[r], vmax);
            float za = 0.f;
#pragma unroll
            for (int sf = 0; sf < 8; sf++) za += __expf(lv[sf][r] - mn);
            z_run[r] = z_run[r] * __expf(m_run[r] - mn) + za;
            m_run[r] = mn;
        }
    }
#pragma unroll
    for (int mask = 1; mask <= 8; mask <<= 1) {
#pragma unroll
        for (int r = 0; r < 4; r++) {
            float om = __shfl_xor(m_run[r], mask, 64);
            float oz = __shfl_xor(z_run[r], mask, 64);
            float mn = fmaxf(m_run[r], om);
            z_run[r] = z_run[r] * __expf(m_run[r] - mn) + oz * __expf(om - mn);
            m_run[r] = mn;
        }
    }
    if (c == 0) {
#pragma unroll
        for (int r = 0; r < 4; r++) {
            const int t = t0 + w * 16 + q * 4 + r;
            mOut[(size_t)bh * Tv + t] = m_run[r];
            zOut[(size_t)bh * Tv + t] = 1.f / z_run[r];
        }
    }
}

// ---------------- attention output: pipelined K/Q, V in regs, swizzled Pt ----------------
__global__ __launch_bounds__(256, 2) void attn_out(
    const short* __restrict__ Qb, const short* __restrict__ Kt, const short* __restrict__ Vt,
    const float* __restrict__ temp, const float* __restrict__ mIn, const float* __restrict__ zIn,
    float* __restrict__ out)
{
    // XCD remap: 8 s-blocks of one (b,h) share K/Q -> same id mod 8.
    const int L = blockIdx.x + 8 * (blockIdx.y + 16 * blockIdx.z);
    const int bh = (L & 7) + 8 * (L >> 6);
    const int s0 = ((L >> 3) & 7) * 128;
    const int b = bh >> 4, h = bh & 15;
    const float ts = temp[h];

    // [0,8192): Vs (prologue) aliased as Pt (main loop)
    // [8192,24576): K/Q double buffer (per buf: Ks 4096 + Qs 4096 shorts)
    // [24576,28672): m[1024], z[1024] floats
    __shared__ short smem[28672];
    short* VsPt = smem;
    float* msz = (float*)(smem + 24576);

    const int tid = threadIdx.x;
    const int lane = tid & 63, w = tid >> 6;
    const int q = lane >> 4, c = lane & 15;
    const short* Vbase = Vt + (size_t)bh * 65536;
    const short* Kbase = Kt + (size_t)bh * 65536;
    const short* Qbase = Qb + (size_t)(b * Tv + h * DHv) * Dv;

    int kOff[2], qOff[2], dK[2], dQ[2];
#pragma unroll
    for (int p = 0; p < 2; p++) {
        const int idx = p * 256 + tid;
        const int r = idx >> 3, cs = idx & 7, cg = cs ^ (r & 7);
        kOff[p] = r * 64 + cg * 8;
        qOff[p] = r * 1024 + cg * 8;
        dK[p] = idx * 8;
        dQ[p] = 4096 + idx * 8;
    }

    // prologue: V(4) + m/z(2) + KQ0(4)
#pragma unroll
    for (int p = 0; p < 4; p++) {
        const int idx = p * 256 + tid;
        const int r = idx >> 3, cs = idx & 7, cg = cs ^ (r & 7);
        async16(Vbase + (size_t)(s0 + r) * 64 + cg * 8, VsPt + idx * 8);
    }
    async16(mIn + (size_t)bh * Tv + tid * 4, (short*)msz + tid * 8);
    async16(zIn + (size_t)bh * Tv + tid * 4, (short*)(msz + 1024) + tid * 8);
#pragma unroll
    for (int p = 0; p < 2; p++) {
        async16(Kbase + kOff[p], smem + 8192 + dK[p]);
        async16(Qbase + qOff[p], smem + 8192 + dQ[p]);
    }
    __syncthreads();

    // V tile -> registers (iteration-invariant MFMA B-operands)
    short8 vb0[8], vb1[8];
#pragma unroll
    for (int sf = 0; sf < 8; sf++) {
        vb0[sf] = frag64(VsPt, sf * 16 + c, q);
        vb1[sf] = frag64(VsPt, sf * 16 + c, 4 + q);
    }

    f32x4 acc[8] = {};
    short* Pt = VsPt;

#pragma unroll 1
    for (int i = 0; i < 16; i++) {
        const short* kq = smem + 8192 + (i & 1) * 8192;
        __syncthreads();   // KQ(i) resident; V-frags read (i==0); Qs/Pt of i-1 fully consumed
        if (i < 15) {      // prefetch KQ(i+1): in flight across BOTH barriers of this iter
            short* nxt = smem + 8192 + ((i + 1) & 1) * 8192;
            const int t1 = (i + 1) * 64;
#pragma unroll
            for (int p = 0; p < 2; p++) {
                async16(Kbase + t1 * 64 + kOff[p], nxt + dK[p]);
                async16(Qbase + t1 + qOff[p], nxt + dQ[p]);
            }
        }
        // phase A: S = K^T V, P = exp(S*ts - m) / Z, store swizzled Pt
        short8 aK0 = frag64(kq, w * 16 + c, q);
        short8 aK1 = frag64(kq, w * 16 + c, 4 + q);
        const int tr0 = i * 64 + w * 16 + q * 4;
        const float4 mv = *(const float4*)&msz[tr0];
        const float4 zv = *(const float4*)&msz[1024 + tr0];
#pragma unroll
        for (int sf = 0; sf < 8; sf++) {
            f32x4 l = {0.f, 0.f, 0.f, 0.f};
            l = MFMA16(aK0, vb0[sf], l);
            l = MFMA16(aK1, vb1[sf], l);
            const int rr = sf * 16 + c;
            short4v p4;
            p4[0] = f2bf(__expf(l[0] * ts - mv.x) * zv.x);
            p4[1] = f2bf(__expf(l[1] * ts - mv.y) * zv.y);
            p4[2] = f2bf(__expf(l[2] * ts - mv.z) * zv.z);
            p4[3] = f2bf(__expf(l[3] * ts - mv.w) * zv.w);
            *(short4v*)&Pt[rr * 64 + (((w * 2 + (q >> 1)) ^ (rr & 7)) << 3) + (q & 1) * 4] = p4;
        }
        lds_barrier();     // Pt visible; does NOT drain the KQ(i+1) prefetch
        // phase B: acc += Q * P
        const short* Qs = kq + 4096;
        short8 aQ0 = frag64(Qs, w * 16 + c, q);
        short8 aQ1 = frag64(Qs, w * 16 + c, 4 + q);
        __builtin_amdgcn_s_setprio(1);
#pragma unroll
        for (int sf = 0; sf < 8; sf++) {
            short8 p0 = frag64(Pt, sf * 16 + c, q);
            short8 p1 = frag64(Pt, sf * 16 + c, 4 + q);
            acc[sf] = MFMA16(aQ0, p0, acc[sf]);
            acc[sf] = MFMA16(aQ1, p1, acc[sf]);
        }
        __builtin_amdgcn_s_setprio(0);
    }

#pragma unroll
    for (int sf = 0; sf < 8; sf++) {
#pragma unroll
        for (int r = 0; r < 4; r++) {
            const int d = w * 16 + q * 4 + r;
            out[(size_t)(b * Tv + h * DHv + d) * Dv + s0 + sf * 16 + c] = acc[sf][r];
        }
    }
}

extern "C" void kernel_launch(void* const* d_in, const int* in_sizes, int n_in,
                              void* d_out, int out_size, void* d_ws, size_t ws_size,
                              hipStream_t stream) {
    const float* x    = (const float*)d_in[0];
    const float* Wq   = (const float*)d_in[1];
    const float* bq   = (const float*)d_in[2];
    const float* Wk   = (const float*)d_in[3];
    const float* bk   = (const float*)d_in[4];
    const float* Wv   = (const float*)d_in[5];
    const float* bv   = (const float*)d_in[6];
    const float* temp = (const float*)d_in[7];
    float* out = (float*)d_out;

    char* ws = (char*)d_ws;
    short* xb = (short*)(ws);                       // [0, 8M)
    short* Wt = (short*)(ws + ((size_t)8 << 20));   // [8M, 14M)
    short* Qb = (short*)(ws + ((size_t)14 << 20));  // [14M, 22M)
    short* Kt = (short*)(ws + ((size_t)22 << 20));  // [22M, 30M)
    short* Vt = (short*)(ws + ((size_t)30 << 20));  // [30M, 38M)
    float* mbuf = (float*)(ws + ((size_t)38 << 20));
    float* zbuf = mbuf + 65536;

    cast_x<<<4096, 256, 0, stream>>>(x, xb);
    w_cast_t<<<dim3(16, 16, 3), 256, 0, stream>>>(Wq, Wk, Wv, Wt);
    qkv_mfma<<<dim3(4, 16, 3), 512, 0, stream>>>(xb, Wt, bq, bk, bv, Qb, Kt, Vt);
    attn_stats<<<dim3(16, 16, 4), 256, 0, stream>>>(Kt, Vt, temp, mbuf, zbuf);
    attn_out<<<dim3(8, 16, 4), 256, 0, stream>>>(Qb, Kt, Vt, temp, mbuf, zbuf, out);
}

// Round 5
// 166.544 us; speedup vs baseline: 1.1720x; 1.0621x over previous
//
#include <hip/hip_runtime.h>
#include <math.h>

#define Bv 4
#define Tv 1024
#define Dv 1024
#define Hv 16
#define DHv 64
#define L2E 1.4426950408889634f

typedef __attribute__((ext_vector_type(8))) short short8;
typedef __attribute__((ext_vector_type(4))) short short4v;
typedef __attribute__((ext_vector_type(4))) float f32x4;

#define MFMA16(a, b, c) __builtin_amdgcn_mfma_f32_16x16x32_bf16((a), (b), (c), 0, 0, 0)

__device__ __forceinline__ short f2bf(float f) {
    union { float f; unsigned u; } v; v.f = f;
    unsigned r = v.u + 0x7FFFu + ((v.u >> 16) & 1u);
    return (short)(r >> 16);
}

// hardware exp2/log2 via compiler-known builtins (proper hazard/dependency modeling)
__device__ __forceinline__ float exp2_hw(float x) {
#if __has_builtin(__builtin_amdgcn_exp2f)
    return __builtin_amdgcn_exp2f(x);
#else
    return exp2f(x);
#endif
}
__device__ __forceinline__ float log2_hw(float x) {
#if __has_builtin(__builtin_amdgcn_logf)
    return __builtin_amdgcn_logf(x);
#else
    return log2f(x);
#endif
}

__device__ __forceinline__ void async16(const void* g, void* l) {
    __builtin_amdgcn_global_load_lds(
        (const __attribute__((address_space(1))) void*)g,
        (__attribute__((address_space(3))) void*)l, 16, 0, 0);
}

// Fragment read from a 64-short-wide tile stored with chunk-XOR swizzle
// (chunk cw of row r lives at slot cw ^ (r&7)). 2-way bank aliasing only.
__device__ __forceinline__ short8 frag64(const short* buf, int r, int cw) {
    return *(const short8*)&buf[r * 64 + ((cw ^ (r & 7)) << 3)];
}

// 32-short-wide (BK=32) variant: 4 chunks per row, slot = (cw ^ r) & 3.
__device__ __forceinline__ short8 frag32(const short* buf, int r, int cw) {
    return *(const short8*)&buf[r * 32 + (((cw ^ r) & 3) << 3)];
}

// lgkmcnt-only barrier: makes same-iteration LDS writes visible WITHOUT
// draining in-flight global_load_lds prefetches (vmcnt untouched).
__device__ __forceinline__ void lds_barrier() {
    asm volatile("s_waitcnt lgkmcnt(0)" ::: "memory");
    __builtin_amdgcn_sched_barrier(0);
    __builtin_amdgcn_s_barrier();
    __builtin_amdgcn_sched_barrier(0);
}

// ---------------- cast x -> bf16 ----------------
__global__ __launch_bounds__(256) void cast_x(const float* __restrict__ x, short* __restrict__ xb) {
    const int idx = blockIdx.x * 256 + threadIdx.x;
    float4 v = ((const float4*)x)[idx];
    short4v o;
    o[0] = f2bf(v.x); o[1] = f2bf(v.y); o[2] = f2bf(v.z); o[3] = f2bf(v.w);
    ((short4v*)xb)[idx] = o;
}

// ---------------- cast + transpose W -> Wt[n][k] bf16 ----------------
__global__ __launch_bounds__(256) void w_cast_t(
    const float* __restrict__ Wq, const float* __restrict__ Wk, const float* __restrict__ Wv,
    short* __restrict__ Wt)
{
    const float* W = (blockIdx.z == 0) ? Wq : (blockIdx.z == 1) ? Wk : Wv;
    short* Wto = Wt + (size_t)blockIdx.z * 1048576;
    __shared__ short Tl[64 * 72];
    const int k0 = blockIdx.y * 64, n0 = blockIdx.x * 64;
    const int tid = threadIdx.x;
    {
        const int r = tid >> 2, c16 = (tid & 3) * 16;
        const float* src = W + (size_t)(k0 + r) * Dv + n0 + c16;
        float4 f0 = ((const float4*)src)[0], f1 = ((const float4*)src)[1];
        float4 f2 = ((const float4*)src)[2], f3 = ((const float4*)src)[3];
        short8 s0, s1;
        s0[0] = f2bf(f0.x); s0[1] = f2bf(f0.y); s0[2] = f2bf(f0.z); s0[3] = f2bf(f0.w);
        s0[4] = f2bf(f1.x); s0[5] = f2bf(f1.y); s0[6] = f2bf(f1.z); s0[7] = f2bf(f1.w);
        s1[0] = f2bf(f2.x); s1[1] = f2bf(f2.y); s1[2] = f2bf(f2.z); s1[3] = f2bf(f2.w);
        s1[4] = f2bf(f3.x); s1[5] = f2bf(f3.y); s1[6] = f2bf(f3.z); s1[7] = f2bf(f3.w);
        *(short8*)&Tl[r * 72 + c16] = s0;
        *(short8*)&Tl[r * 72 + c16 + 8] = s1;
    }
    __syncthreads();
#pragma unroll
    for (int p = 0; p < 2; p++) {
        const int n = p * 32 + (tid >> 3), j8 = (tid & 7) * 8;
        short8 o;
#pragma unroll
        for (int jj = 0; jj < 8; jj++) o[jj] = Tl[(j8 + jj) * 72 + n];
        *(short8*)&Wto[(size_t)(n0 + n) * Dv + k0 + j8] = o;
    }
}

// ---------------- QKV projection: 256x256 tile, BK=32, 3-deep pipeline ----------------
__device__ __forceinline__ void stage_tile(
    const short* __restrict__ xb, const short* __restrict__ Wt,
    const int* aOff, const int* bOff, const int* dOff,
    short* smem, int sl, int k)
{
#pragma unroll
    for (int p = 0; p < 2; p++) {
        async16(xb + aOff[p] + k, smem + sl + dOff[p]);
        async16(Wt + bOff[p] + k, smem + 24576 + sl + dOff[p]);
    }
}

__device__ __forceinline__ void compute_tile(
    const short* smem, int sl, int RM, int CN, int c, int q, f32x4 acc[8][4])
{
    const short* Ac = smem + sl;
    const short* Bc = smem + 24576 + sl;
    short8 bf[4], af[8];
#pragma unroll
    for (int j = 0; j < 4; j++) bf[j] = frag32(Bc, CN + j * 16 + c, q);
#pragma unroll
    for (int m = 0; m < 8; m++) af[m] = frag32(Ac, RM + m * 16 + c, q);
    __builtin_amdgcn_s_setprio(1);
#pragma unroll
    for (int m = 0; m < 8; m++)
#pragma unroll
        for (int j = 0; j < 4; j++)
            acc[m][j] = MFMA16(af[m], bf[j], acc[m][j]);
    __builtin_amdgcn_s_setprio(0);
}

// z=0: Q natural. z=1: K, pre-scaled by temperature[h]*log2(e), transposed per head.
// z=2: V transposed per head.
__global__ __launch_bounds__(512, 2) void qkv_mfma(
    const short* __restrict__ xb, const short* __restrict__ Wt3,
    const float* __restrict__ bq, const float* __restrict__ bk, const float* __restrict__ bv,
    const float* __restrict__ temp,
    short* __restrict__ Qo, short* __restrict__ Kt, short* __restrict__ Vt)
{
    const int z = blockIdx.z;
    const short* Wt = Wt3 + (size_t)z * 1048576;
    const float* bias = (z == 0) ? bq : (z == 1) ? bk : bv;

    __shared__ short smem[49152];

    const int tid = threadIdx.x;
    const int lane = tid & 63, w = tid >> 6;
    const int q = lane >> 4, c = lane & 15;
    const int wr = w >> 2, wc = w & 3;
    const int RM = wr * 128, CN = wc * 64;
    const int bm = blockIdx.y * 256, bn = blockIdx.x * 256;

    int aOff[2], bOff[2], dOff[2];
#pragma unroll
    for (int p = 0; p < 2; p++) {
        const int idx = p * 512 + tid;
        const int r = idx >> 2, cs = idx & 3, cg = (cs ^ r) & 3;
        aOff[p] = (bm + r) * Dv + cg * 8;
        bOff[p] = (bn + r) * Dv + cg * 8;
        dOff[p] = idx * 8;
    }

    f32x4 acc[8][4] = {};

    stage_tile(xb, Wt, aOff, bOff, dOff, smem, 0, 0);
    stage_tile(xb, Wt, aOff, bOff, dOff, smem, 8192, 32);

    int slC = 0, slS = 16384;
#pragma unroll 1
    for (int i = 0; i < 30; i++) {
        asm volatile("s_waitcnt vmcnt(4)" ::: "memory");
        __builtin_amdgcn_s_barrier();
        __builtin_amdgcn_sched_barrier(0);
        stage_tile(xb, Wt, aOff, bOff, dOff, smem, slS, (i + 2) * 32);
        compute_tile(smem, slC, RM, CN, c, q, acc);
        slC += 8192; if (slC == 24576) slC = 0;
        slS += 8192; if (slS == 24576) slS = 0;
    }
    asm volatile("s_waitcnt vmcnt(4)" ::: "memory");
    __builtin_amdgcn_s_barrier();
    __builtin_amdgcn_sched_barrier(0);
    compute_tile(smem, slC, RM, CN, c, q, acc);
    slC += 8192; if (slC == 24576) slC = 0;
    asm volatile("s_waitcnt vmcnt(0)" ::: "memory");
    __builtin_amdgcn_s_barrier();
    __builtin_amdgcn_sched_barrier(0);
    compute_tile(smem, slC, RM, CN, c, q, acc);

    if (z == 0) {
#pragma unroll
        for (int j = 0; j < 4; j++) {
            const int col = bn + CN + j * 16 + c;
            const float bb = bias[col];
#pragma unroll
            for (int m = 0; m < 8; m++) {
#pragma unroll
                for (int r = 0; r < 4; r++) {
                    const int row = bm + RM + m * 16 + q * 4 + r;
                    Qo[(size_t)row * Dv + col] = f2bf(acc[m][j][r] + bb);
                }
            }
        }
    } else {
        // per-row (token) scale: rows bm+RM+[0,64) are head h0, +[64,128) head h0+1
        float scl[2] = {1.f, 1.f};
        if (z == 1) {
            const int h0 = ((bm + RM) >> 6) & 15;
            scl[0] = temp[h0] * L2E;
            scl[1] = temp[(h0 + 1) & 15] * L2E;
        }
        short* dst = (z == 1) ? Kt : Vt;
        short* T = smem;
        const int hb = bm >> 6;
#pragma unroll
        for (int nh = 0; nh < 2; nh++) {
            __syncthreads();
            if ((wc >> 1) == nh) {
#pragma unroll
                for (int j = 0; j < 4; j++) {
                    const int nl = (wc & 1) * 64 + j * 16 + c;
                    const float bb = bias[bn + nh * 128 + nl];
#pragma unroll
                    for (int m = 0; m < 8; m++) {
                        const float s = scl[m >> 2];
                        short4v pk;
#pragma unroll
                        for (int r = 0; r < 4; r++) pk[r] = f2bf((acc[m][j][r] + bb) * s);
                        *(short4v*)&T[nl * 264 + RM + m * 16 + q * 4] = pk;
                    }
                }
            }
            __syncthreads();
#pragma unroll
            for (int p = 0; p < 8; p++) {
                const int idx = p * 512 + tid;
                const int n = idx >> 5, k2 = idx & 31;
                short8 v = *(const short8*)&T[n * 264 + k2 * 8];
                const size_t addr = (size_t)(hb + (k2 >> 3)) * 65536 +
                                    (size_t)(bn + nh * 128 + n) * 64 + (k2 & 7) * 8;
                *(short8*)&dst[addr] = v;
            }
        }
    }
}

// ---------------- attention stats: mz[t] = log2( sum_s exp2(l[t,s]) ) ----------------
// K is pre-scaled by ts*log2e, so l is the exp2-domain logit. No max needed:
// |l| <= ~30 here, f32 range 2^127 -- huge margin. Mathematically identical softmax.
__global__ __launch_bounds__(256, 4) void attn_stats(
    const short* __restrict__ Kt, const short* __restrict__ Vt,
    float* __restrict__ mzOut)
{
    // XCD remap: the 16 t-blocks of one (b,h) share V -> same id mod 8 (same XCD L2).
    const int L = blockIdx.x + 16 * (blockIdx.y + 16 * blockIdx.z);
    const int bh = (L & 7) + 8 * (L >> 7);
    const int t0 = ((L >> 3) & 15) * 64;
    __shared__ short Ks[64 * 64];
    __shared__ short Vs[2][128 * 64];
    const int tid = threadIdx.x;
    const int lane = tid & 63, w = tid >> 6;
    const int q = lane >> 4, c = lane & 15;
    const short* Kbase = Kt + (size_t)bh * 65536;
    const short* Vbase = Vt + (size_t)bh * 65536;

    int vOff[4], vDst[4];
#pragma unroll
    for (int p = 0; p < 4; p++) {
        const int idx = p * 256 + tid;
        const int r = idx >> 3, cs = idx & 7, cg = cs ^ (r & 7);
        vOff[p] = r * 64 + cg * 8;
        vDst[p] = idx * 8;
    }
#pragma unroll
    for (int p = 0; p < 2; p++) {
        const int idx = p * 256 + tid;
        const int r = idx >> 3, cs = idx & 7, cg = cs ^ (r & 7);
        async16(Kbase + (size_t)(t0 + r) * 64 + cg * 8, Ks + idx * 8);
    }
#pragma unroll
    for (int p = 0; p < 4; p++) async16(Vbase + vOff[p], &Vs[0][0] + vDst[p]);

    float z_run[4] = {0.f, 0.f, 0.f, 0.f};

    short8 aK0, aK1;
#pragma unroll 1
    for (int i = 0; i < 8; i++) {
        __syncthreads();                       // V(i) resident everywhere
        if (i < 7) {                           // prefetch V(i+1); drains at NEXT iter top
            const short* src = Vbase + (i + 1) * 8192;
#pragma unroll
            for (int p = 0; p < 4; p++) async16(src + vOff[p], &Vs[(i + 1) & 1][0] + vDst[p]);
        }
        if (i == 0) {
            aK0 = frag64(Ks, w * 16 + c, q);
            aK1 = frag64(Ks, w * 16 + c, 4 + q);
        }
        const short* Vc = &Vs[i & 1][0];
        __builtin_amdgcn_s_setprio(1);
#pragma unroll
        for (int sf = 0; sf < 8; sf++) {
            short8 b0 = frag64(Vc, sf * 16 + c, q);
            short8 b1 = frag64(Vc, sf * 16 + c, 4 + q);
            f32x4 l = {0.f, 0.f, 0.f, 0.f};
            l = MFMA16(aK0, b0, l);
            l = MFMA16(aK1, b1, l);
#pragma unroll
            for (int r = 0; r < 4; r++) z_run[r] += exp2_hw(l[r]);
        }
        __builtin_amdgcn_s_setprio(0);
    }
#pragma unroll
    for (int mask = 1; mask <= 8; mask <<= 1) {
#pragma unroll
        for (int r = 0; r < 4; r++) z_run[r] += __shfl_xor(z_run[r], mask, 64);
    }
    if (c == 0) {
#pragma unroll
        for (int r = 0; r < 4; r++) {
            const int t = t0 + w * 16 + q * 4 + r;
            mzOut[(size_t)bh * Tv + t] = log2_hw(z_run[r]);
        }
    }
}

// ---------------- attention output: P = exp2(l - mz), pipelined K/Q, V in regs ----------------
__global__ __launch_bounds__(256, 2) void attn_out(
    const short* __restrict__ Qb, const short* __restrict__ Kt, const short* __restrict__ Vt,
    const float* __restrict__ mzIn, float* __restrict__ out)
{
    // XCD remap: 8 s-blocks of one (b,h) share K/Q -> same id mod 8.
    const int L = blockIdx.x + 8 * (blockIdx.y + 16 * blockIdx.z);
    const int bh = (L & 7) + 8 * (L >> 6);
    const int s0 = ((L >> 3) & 7) * 128;
    const int b = bh >> 4, h = bh & 15;

    // [0,8192): Vs (prologue) aliased as Pt (main loop)
    // [8192,24576): K/Q double buffer (per buf: Ks 4096 + Qs 4096 shorts)
    // [24576,26624): mz[1024] floats
    __shared__ short smem[26624];
    short* VsPt = smem;
    float* mzs = (float*)(smem + 24576);

    const int tid = threadIdx.x;
    const int lane = tid & 63, w = tid >> 6;
    const int q = lane >> 4, c = lane & 15;
    const short* Vbase = Vt + (size_t)bh * 65536;
    const short* Kbase = Kt + (size_t)bh * 65536;
    const short* Qbase = Qb + (size_t)(b * Tv + h * DHv) * Dv;

    int kOff[2], qOff[2], dK[2], dQ[2];
#pragma unroll
    for (int p = 0; p < 2; p++) {
        const int idx = p * 256 + tid;
        const int r = idx >> 3, cs = idx & 7, cg = cs ^ (r & 7);
        kOff[p] = r * 64 + cg * 8;
        qOff[p] = r * 1024 + cg * 8;
        dK[p] = idx * 8;
        dQ[p] = 4096 + idx * 8;
    }

    // prologue: V(4) + mz(1) + KQ0(4)
#pragma unroll
    for (int p = 0; p < 4; p++) {
        const int idx = p * 256 + tid;
        const int r = idx >> 3, cs = idx & 7, cg = cs ^ (r & 7);
        async16(Vbase + (size_t)(s0 + r) * 64 + cg * 8, VsPt + idx * 8);
    }
    async16(mzIn + (size_t)bh * Tv + tid * 4, (short*)mzs + tid * 8);
#pragma unroll
    for (int p = 0; p < 2; p++) {
        async16(Kbase + kOff[p], smem + 8192 + dK[p]);
        async16(Qbase + qOff[p], smem + 8192 + dQ[p]);
    }
    __syncthreads();

    // V tile -> registers (iteration-invariant MFMA B-operands)
    short8 vb0[8], vb1[8];
#pragma unroll
    for (int sf = 0; sf < 8; sf++) {
        vb0[sf] = frag64(VsPt, sf * 16 + c, q);
        vb1[sf] = frag64(VsPt, sf * 16 + c, 4 + q);
    }

    f32x4 acc[8] = {};
    short* Pt = VsPt;

#pragma unroll 1
    for (int i = 0; i < 16; i++) {
        const short* kq = smem + 8192 + (i & 1) * 8192;
        __syncthreads();   // KQ(i) resident; V-frags read (i==0); Qs/Pt of i-1 fully consumed
        if (i < 15) {      // prefetch KQ(i+1): in flight across BOTH barriers of this iter
            short* nxt = smem + 8192 + ((i + 1) & 1) * 8192;
            const int t1 = (i + 1) * 64;
#pragma unroll
            for (int p = 0; p < 2; p++) {
                async16(Kbase + t1 * 64 + kOff[p], nxt + dK[p]);
                async16(Qbase + t1 + qOff[p], nxt + dQ[p]);
            }
        }
        // phase A: l = (K*ts*log2e)^T V;  P = exp2(l - mz);  store swizzled Pt
        short8 aK0 = frag64(kq, w * 16 + c, q);
        short8 aK1 = frag64(kq, w * 16 + c, 4 + q);
        const int tr0 = i * 64 + w * 16 + q * 4;
        const float4 mv = *(const float4*)&mzs[tr0];
#pragma unroll
        for (int sf = 0; sf < 8; sf++) {
            f32x4 l = {0.f, 0.f, 0.f, 0.f};
            l = MFMA16(aK0, vb0[sf], l);
            l = MFMA16(aK1, vb1[sf], l);
            const int rr = sf * 16 + c;
            short4v p4;
            p4[0] = f2bf(exp2_hw(l[0] - mv.x));
            p4[1] = f2bf(exp2_hw(l[1] - mv.y));
            p4[2] = f2bf(exp2_hw(l[2] - mv.z));
            p4[3] = f2bf(exp2_hw(l[3] - mv.w));
            *(short4v*)&Pt[rr * 64 + (((w * 2 + (q >> 1)) ^ (rr & 7)) << 3) + (q & 1) * 4] = p4;
        }
        lds_barrier();     // Pt visible; does NOT drain the KQ(i+1) prefetch
        // phase B: acc += Q * P
        const short* Qs = kq + 4096;
        short8 aQ0 = frag64(Qs, w * 16 + c, q);
        short8 aQ1 = frag64(Qs, w * 16 + c, 4 + q);
        __builtin_amdgcn_s_setprio(1);
#pragma unroll
        for (int sf = 0; sf < 8; sf++) {
            short8 p0 = frag64(Pt, sf * 16 + c, q);
            short8 p1 = frag64(Pt, sf * 16 + c, 4 + q);
            acc[sf] = MFMA16(aQ0, p0, acc[sf]);
            acc[sf] = MFMA16(aQ1, p1, acc[sf]);
        }
        __builtin_amdgcn_s_setprio(0);
    }

#pragma unroll
    for (int sf = 0; sf < 8; sf++) {
#pragma unroll
        for (int r = 0; r < 4; r++) {
            const int d = w * 16 + q * 4 + r;
            out[(size_t)(b * Tv + h * DHv + d) * Dv + s0 + sf * 16 + c] = acc[sf][r];
        }
    }
}

extern "C" void kernel_launch(void* const* d_in, const int* in_sizes, int n_in,
                              void* d_out, int out_size, void* d_ws, size_t ws_size,
                              hipStream_t stream) {
    const float* x    = (const float*)d_in[0];
    const float* Wq   = (const float*)d_in[1];
    const float* bq   = (const float*)d_in[2];
    const float* Wk   = (const float*)d_in[3];
    const float* bk   = (const float*)d_in[4];
    const float* Wv   = (const float*)d_in[5];
    const float* bv   = (const float*)d_in[6];
    const float* temp = (const float*)d_in[7];
    float* out = (float*)d_out;

    char* ws = (char*)d_ws;
    short* xb = (short*)(ws);                       // [0, 8M)
    short* Wt = (short*)(ws + ((size_t)8 << 20));   // [8M, 14M)
    short* Qb = (short*)(ws + ((size_t)14 << 20));  // [14M, 22M)
    short* Kt = (short*)(ws + ((size_t)22 << 20));  // [22M, 30M)
    short* Vt = (short*)(ws + ((size_t)30 << 20));  // [30M, 38M)
    float* mzbuf = (float*)(ws + ((size_t)38 << 20));

    cast_x<<<4096, 256, 0, stream>>>(x, xb);
    w_cast_t<<<dim3(16, 16, 3), 256, 0, stream>>>(Wq, Wk, Wv, Wt);
    qkv_mfma<<<dim3(4, 16, 3), 512, 0, stream>>>(xb, Wt, bq, bk, bv, temp, Qb, Kt, Vt);
    attn_stats<<<dim3(16, 16, 4), 256, 0, stream>>>(Kt, Vt, mzbuf);
    attn_out<<<dim3(8, 16, 4), 256, 0, stream>>>(Qb, Kt, Vt, mzbuf, out);
}

// Round 6
// 160.659 us; speedup vs baseline: 1.2149x; 1.0366x over previous
//
#include <hip/hip_runtime.h>
#include <math.h>

#define Bv 4
#define Tv 1024
#define Dv 1024
#define Hv 16
#define DHv 64
#define L2E 1.4426950408889634f

typedef __attribute__((ext_vector_type(8))) short short8;
typedef __attribute__((ext_vector_type(4))) short short4v;
typedef __attribute__((ext_vector_type(4))) float f32x4;
typedef __attribute__((ext_vector_type(2))) int int2v;

#define MFMA16(a, b, c) __builtin_amdgcn_mfma_f32_16x16x32_bf16((a), (b), (c), 0, 0, 0)

__device__ __forceinline__ short f2bf(float f) {
    union { float f; unsigned u; } v; v.f = f;
    unsigned r = v.u + 0x7FFFu + ((v.u >> 16) & 1u);
    return (short)(r >> 16);
}

// hardware exp2/log2 via compiler-known builtins (proper TRANS-hazard modeling)
__device__ __forceinline__ float exp2_hw(float x) {
#if __has_builtin(__builtin_amdgcn_exp2f)
    return __builtin_amdgcn_exp2f(x);
#else
    return exp2f(x);
#endif
}
__device__ __forceinline__ float log2_hw(float x) {
#if __has_builtin(__builtin_amdgcn_logf)
    return __builtin_amdgcn_logf(x);
#else
    return log2f(x);
#endif
}

// packed bf16 convert (RTNE, same rounding as f2bf). Non-TRANS VOP3: no hazard class.
__device__ __forceinline__ int cvt_pk_bf16(float lo, float hi) {
    int r; asm("v_cvt_pk_bf16_f32 %0, %1, %2" : "=v"(r) : "v"(lo), "v"(hi)); return r;
}

__device__ __forceinline__ void async16(const void* g, void* l) {
    __builtin_amdgcn_global_load_lds(
        (const __attribute__((address_space(1))) void*)g,
        (__attribute__((address_space(3))) void*)l, 16, 0, 0);
}

// Fragment read from a 64-short-wide tile stored with chunk-XOR swizzle
// (chunk cw of row r lives at slot cw ^ (r&7)). 2-way bank aliasing only.
__device__ __forceinline__ short8 frag64(const short* buf, int r, int cw) {
    return *(const short8*)&buf[r * 64 + ((cw ^ (r & 7)) << 3)];
}

// 32-short-wide (BK=32) variant: 4 chunks per row, slot = (cw ^ (r>>1)) & 3.
// NOTE (r>>1): a 32-short row is 16 dwords, so r&1 already selects the bank half;
// swizzling on r (not r>>1) collapses same-parity rows onto 2 slots -> 4-way
// conflict. r>>1 spreads them over all 4 slots -> 2-way (free).
__device__ __forceinline__ short8 frag32(const short* buf, int r, int cw) {
    return *(const short8*)&buf[r * 32 + (((cw ^ (r >> 1)) & 3) << 3)];
}

// lgkmcnt-only barrier: makes same-iteration LDS writes visible WITHOUT
// draining in-flight global_load_lds prefetches (vmcnt untouched).
__device__ __forceinline__ void lds_barrier() {
    asm volatile("s_waitcnt lgkmcnt(0)" ::: "memory");
    __builtin_amdgcn_sched_barrier(0);
    __builtin_amdgcn_s_barrier();
    __builtin_amdgcn_sched_barrier(0);
}

// ---------------- cast x -> bf16 ----------------
__global__ __launch_bounds__(256) void cast_x(const float* __restrict__ x, short* __restrict__ xb) {
    const int idx = blockIdx.x * 256 + threadIdx.x;
    float4 v = ((const float4*)x)[idx];
    short4v o;
    o[0] = f2bf(v.x); o[1] = f2bf(v.y); o[2] = f2bf(v.z); o[3] = f2bf(v.w);
    ((short4v*)xb)[idx] = o;
}

// ---------------- cast + transpose W -> Wt[n][k] bf16 ----------------
__global__ __launch_bounds__(256) void w_cast_t(
    const float* __restrict__ Wq, const float* __restrict__ Wk, const float* __restrict__ Wv,
    short* __restrict__ Wt)
{
    const float* W = (blockIdx.z == 0) ? Wq : (blockIdx.z == 1) ? Wk : Wv;
    short* Wto = Wt + (size_t)blockIdx.z * 1048576;
    __shared__ short Tl[64 * 72];
    const int k0 = blockIdx.y * 64, n0 = blockIdx.x * 64;
    const int tid = threadIdx.x;
    {
        const int r = tid >> 2, c16 = (tid & 3) * 16;
        const float* src = W + (size_t)(k0 + r) * Dv + n0 + c16;
        float4 f0 = ((const float4*)src)[0], f1 = ((const float4*)src)[1];
        float4 f2 = ((const float4*)src)[2], f3 = ((const float4*)src)[3];
        short8 s0, s1;
        s0[0] = f2bf(f0.x); s0[1] = f2bf(f0.y); s0[2] = f2bf(f0.z); s0[3] = f2bf(f0.w);
        s0[4] = f2bf(f1.x); s0[5] = f2bf(f1.y); s0[6] = f2bf(f1.z); s0[7] = f2bf(f1.w);
        s1[0] = f2bf(f2.x); s1[1] = f2bf(f2.y); s1[2] = f2bf(f2.z); s1[3] = f2bf(f2.w);
        s1[4] = f2bf(f3.x); s1[5] = f2bf(f3.y); s1[6] = f2bf(f3.z); s1[7] = f2bf(f3.w);
        *(short8*)&Tl[r * 72 + c16] = s0;
        *(short8*)&Tl[r * 72 + c16 + 8] = s1;
    }
    __syncthreads();
#pragma unroll
    for (int p = 0; p < 2; p++) {
        const int n = p * 32 + (tid >> 3), j8 = (tid & 7) * 8;
        short8 o;
#pragma unroll
        for (int jj = 0; jj < 8; jj++) o[jj] = Tl[(j8 + jj) * 72 + n];
        *(short8*)&Wto[(size_t)(n0 + n) * Dv + k0 + j8] = o;
    }
}

// ---------------- QKV projection: 256x256 tile, BK=32, 3-deep pipeline ----------------
__device__ __forceinline__ void stage_tile(
    const short* __restrict__ xb, const short* __restrict__ Wt,
    const int* aOff, const int* bOff, const int* dOff,
    short* smem, int sl, int k)
{
#pragma unroll
    for (int p = 0; p < 2; p++) {
        async16(xb + aOff[p] + k, smem + sl + dOff[p]);
        async16(Wt + bOff[p] + k, smem + 24576 + sl + dOff[p]);
    }
}

__device__ __forceinline__ void compute_tile(
    const short* smem, int sl, int RM, int CN, int c, int q, f32x4 acc[8][4])
{
    const short* Ac = smem + sl;
    const short* Bc = smem + 24576 + sl;
    short8 bf[4], af[8];
#pragma unroll
    for (int j = 0; j < 4; j++) bf[j] = frag32(Bc, CN + j * 16 + c, q);
#pragma unroll
    for (int m = 0; m < 8; m++) af[m] = frag32(Ac, RM + m * 16 + c, q);
    __builtin_amdgcn_s_setprio(1);
#pragma unroll
    for (int m = 0; m < 8; m++)
#pragma unroll
        for (int j = 0; j < 4; j++)
            acc[m][j] = MFMA16(af[m], bf[j], acc[m][j]);
    __builtin_amdgcn_s_setprio(0);
}

// z=0: Q natural. z=1: K, pre-scaled by temperature[h]*log2(e), transposed per head.
// z=2: V transposed per head.
__global__ __launch_bounds__(512, 2) void qkv_mfma(
    const short* __restrict__ xb, const short* __restrict__ Wt3,
    const float* __restrict__ bq, const float* __restrict__ bk, const float* __restrict__ bv,
    const float* __restrict__ temp,
    short* __restrict__ Qo, short* __restrict__ Kt, short* __restrict__ Vt)
{
    const int z = blockIdx.z;
    const short* Wt = Wt3 + (size_t)z * 1048576;
    const float* bias = (z == 0) ? bq : (z == 1) ? bk : bv;

    __shared__ short smem[49152];

    const int tid = threadIdx.x;
    const int lane = tid & 63, w = tid >> 6;
    const int q = lane >> 4, c = lane & 15;
    const int wr = w >> 2, wc = w & 3;
    const int RM = wr * 128, CN = wc * 64;
    const int bm = blockIdx.y * 256, bn = blockIdx.x * 256;

    // staging: pre-swizzle the global source chunk so the linear LDS dest matches
    // frag32's (cw ^ (r>>1)) & 3 slot map.
    int aOff[2], bOff[2], dOff[2];
#pragma unroll
    for (int p = 0; p < 2; p++) {
        const int idx = p * 512 + tid;
        const int r = idx >> 2, cs = idx & 3, cg = (cs ^ (r >> 1)) & 3;
        aOff[p] = (bm + r) * Dv + cg * 8;
        bOff[p] = (bn + r) * Dv + cg * 8;
        dOff[p] = idx * 8;
    }

    f32x4 acc[8][4] = {};

    stage_tile(xb, Wt, aOff, bOff, dOff, smem, 0, 0);
    stage_tile(xb, Wt, aOff, bOff, dOff, smem, 8192, 32);

    int slC = 0, slS = 16384;
#pragma unroll 1
    for (int i = 0; i < 30; i++) {
        asm volatile("s_waitcnt vmcnt(4)" ::: "memory");
        __builtin_amdgcn_s_barrier();
        __builtin_amdgcn_sched_barrier(0);
        stage_tile(xb, Wt, aOff, bOff, dOff, smem, slS, (i + 2) * 32);
        compute_tile(smem, slC, RM, CN, c, q, acc);
        slC += 8192; if (slC == 24576) slC = 0;
        slS += 8192; if (slS == 24576) slS = 0;
    }
    asm volatile("s_waitcnt vmcnt(4)" ::: "memory");
    __builtin_amdgcn_s_barrier();
    __builtin_amdgcn_sched_barrier(0);
    compute_tile(smem, slC, RM, CN, c, q, acc);
    slC += 8192; if (slC == 24576) slC = 0;
    asm volatile("s_waitcnt vmcnt(0)" ::: "memory");
    __builtin_amdgcn_s_barrier();
    __builtin_amdgcn_sched_barrier(0);
    compute_tile(smem, slC, RM, CN, c, q, acc);

    if (z == 0) {
#pragma unroll
        for (int j = 0; j < 4; j++) {
            const int col = bn + CN + j * 16 + c;
            const float bb = bias[col];
#pragma unroll
            for (int m = 0; m < 8; m++) {
#pragma unroll
                for (int r = 0; r < 4; r++) {
                    const int row = bm + RM + m * 16 + q * 4 + r;
                    Qo[(size_t)row * Dv + col] = f2bf(acc[m][j][r] + bb);
                }
            }
        }
    } else {
        // per-row (token) scale: rows bm+RM+[0,64) are head h0, +[64,128) head h0+1
        float scl[2] = {1.f, 1.f};
        if (z == 1) {
            const int h0 = ((bm + RM) >> 6) & 15;
            scl[0] = temp[h0] * L2E;
            scl[1] = temp[(h0 + 1) & 15] * L2E;
        }
        short* dst = (z == 1) ? Kt : Vt;
        short* T = smem;
        const int hb = bm >> 6;
#pragma unroll
        for (int nh = 0; nh < 2; nh++) {
            __syncthreads();
            if ((wc >> 1) == nh) {
#pragma unroll
                for (int j = 0; j < 4; j++) {
                    const int nl = (wc & 1) * 64 + j * 16 + c;
                    const float bb = bias[bn + nh * 128 + nl];
#pragma unroll
                    for (int m = 0; m < 8; m++) {
                        const float s = scl[m >> 2];
                        int2v pk;
                        pk[0] = cvt_pk_bf16((acc[m][j][0] + bb) * s, (acc[m][j][1] + bb) * s);
                        pk[1] = cvt_pk_bf16((acc[m][j][2] + bb) * s, (acc[m][j][3] + bb) * s);
                        *(int2v*)&T[nl * 264 + RM + m * 16 + q * 4] = pk;
                    }
                }
            }
            __syncthreads();
#pragma unroll
            for (int p = 0; p < 8; p++) {
                const int idx = p * 512 + tid;
                const int n = idx >> 5, k2 = idx & 31;
                short8 v = *(const short8*)&T[n * 264 + k2 * 8];
                const size_t addr = (size_t)(hb + (k2 >> 3)) * 65536 +
                                    (size_t)(bn + nh * 128 + n) * 64 + (k2 & 7) * 8;
                *(short8*)&dst[addr] = v;
            }
        }
    }
}

// ---------------- attention stats: mz[t] = log2( sum_s exp2(l[t,s]) ) ----------------
// K is pre-scaled by ts*log2e, so l is the exp2-domain logit. No max needed:
// |l| <= ~30 here, f32 range 2^127 -- huge margin. Mathematically identical softmax.
__global__ __launch_bounds__(256, 4) void attn_stats(
    const short* __restrict__ Kt, const short* __restrict__ Vt,
    float* __restrict__ mzOut)
{
    // XCD remap: the 16 t-blocks of one (b,h) share V -> same id mod 8 (same XCD L2).
    const int L = blockIdx.x + 16 * (blockIdx.y + 16 * blockIdx.z);
    const int bh = (L & 7) + 8 * (L >> 7);
    const int t0 = ((L >> 3) & 15) * 64;
    __shared__ short Ks[64 * 64];
    __shared__ short Vs[2][128 * 64];
    const int tid = threadIdx.x;
    const int lane = tid & 63, w = tid >> 6;
    const int q = lane >> 4, c = lane & 15;
    const short* Kbase = Kt + (size_t)bh * 65536;
    const short* Vbase = Vt + (size_t)bh * 65536;

    int vOff[4], vDst[4];
#pragma unroll
    for (int p = 0; p < 4; p++) {
        const int idx = p * 256 + tid;
        const int r = idx >> 3, cs = idx & 7, cg = cs ^ (r & 7);
        vOff[p] = r * 64 + cg * 8;
        vDst[p] = idx * 8;
    }
#pragma unroll
    for (int p = 0; p < 2; p++) {
        const int idx = p * 256 + tid;
        const int r = idx >> 3, cs = idx & 7, cg = cs ^ (r & 7);
        async16(Kbase + (size_t)(t0 + r) * 64 + cg * 8, Ks + idx * 8);
    }
#pragma unroll
    for (int p = 0; p < 4; p++) async16(Vbase + vOff[p], &Vs[0][0] + vDst[p]);

    float z_run[4] = {0.f, 0.f, 0.f, 0.f};

    short8 aK0, aK1;
#pragma unroll 1
    for (int i = 0; i < 8; i++) {
        __syncthreads();                       // V(i) resident everywhere
        if (i < 7) {                           // prefetch V(i+1); drains at NEXT iter top
            const short* src = Vbase + (i + 1) * 8192;
#pragma unroll
            for (int p = 0; p < 4; p++) async16(src + vOff[p], &Vs[(i + 1) & 1][0] + vDst[p]);
        }
        if (i == 0) {
            aK0 = frag64(Ks, w * 16 + c, q);
            aK1 = frag64(Ks, w * 16 + c, 4 + q);
        }
        const short* Vc = &Vs[i & 1][0];
        __builtin_amdgcn_s_setprio(1);
#pragma unroll
        for (int sf = 0; sf < 8; sf++) {
            short8 b0 = frag64(Vc, sf * 16 + c, q);
            short8 b1 = frag64(Vc, sf * 16 + c, 4 + q);
            f32x4 l = {0.f, 0.f, 0.f, 0.f};
            l = MFMA16(aK0, b0, l);
            l = MFMA16(aK1, b1, l);
#pragma unroll
            for (int r = 0; r < 4; r++) z_run[r] += exp2_hw(l[r]);
        }
        __builtin_amdgcn_s_setprio(0);
    }
#pragma unroll
    for (int mask = 1; mask <= 8; mask <<= 1) {
#pragma unroll
        for (int r = 0; r < 4; r++) z_run[r] += __shfl_xor(z_run[r], mask, 64);
    }
    if (c == 0) {
#pragma unroll
        for (int r = 0; r < 4; r++) {
            const int t = t0 + w * 16 + q * 4 + r;
            mzOut[(size_t)bh * Tv + t] = log2_hw(z_run[r]);
        }
    }
}

// ---------------- attention output: P = exp2(l - mz), pipelined K/Q, V in regs ----------------
__global__ __launch_bounds__(256, 2) void attn_out(
    const short* __restrict__ Qb, const short* __restrict__ Kt, const short* __restrict__ Vt,
    const float* __restrict__ mzIn, float* __restrict__ out)
{
    // XCD remap: 8 s-blocks of one (b,h) share K/Q -> same id mod 8.
    const int L = blockIdx.x + 8 * (blockIdx.y + 16 * blockIdx.z);
    const int bh = (L & 7) + 8 * (L >> 6);
    const int s0 = ((L >> 3) & 7) * 128;
    const int b = bh >> 4, h = bh & 15;

    // [0,8192): Vs (prologue) aliased as Pt (main loop)
    // [8192,24576): K/Q double buffer (per buf: Ks 4096 + Qs 4096 shorts)
    // [24576,26624): mz[1024] floats
    __shared__ short smem[26624];
    short* VsPt = smem;
    float* mzs = (float*)(smem + 24576);

    const int tid = threadIdx.x;
    const int lane = tid & 63, w = tid >> 6;
    const int q = lane >> 4, c = lane & 15;
    const short* Vbase = Vt + (size_t)bh * 65536;
    const short* Kbase = Kt + (size_t)bh * 65536;
    const short* Qbase = Qb + (size_t)(b * Tv + h * DHv) * Dv;

    int kOff[2], qOff[2], dK[2], dQ[2];
#pragma unroll
    for (int p = 0; p < 2; p++) {
        const int idx = p * 256 + tid;
        const int r = idx >> 3, cs = idx & 7, cg = cs ^ (r & 7);
        kOff[p] = r * 64 + cg * 8;
        qOff[p] = r * 1024 + cg * 8;
        dK[p] = idx * 8;
        dQ[p] = 4096 + idx * 8;
    }

    // prologue: V(4) + mz(1) + KQ0(4)
#pragma unroll
    for (int p = 0; p < 4; p++) {
        const int idx = p * 256 + tid;
        const int r = idx >> 3, cs = idx & 7, cg = cs ^ (r & 7);
        async16(Vbase + (size_t)(s0 + r) * 64 + cg * 8, VsPt + idx * 8);
    }
    async16(mzIn + (size_t)bh * Tv + tid * 4, (short*)mzs + tid * 8);
#pragma unroll
    for (int p = 0; p < 2; p++) {
        async16(Kbase + kOff[p], smem + 8192 + dK[p]);
        async16(Qbase + qOff[p], smem + 8192 + dQ[p]);
    }
    __syncthreads();

    // V tile -> registers (iteration-invariant MFMA B-operands)
    short8 vb0[8], vb1[8];
#pragma unroll
    for (int sf = 0; sf < 8; sf++) {
        vb0[sf] = frag64(VsPt, sf * 16 + c, q);
        vb1[sf] = frag64(VsPt, sf * 16 + c, 4 + q);
    }

    f32x4 acc[8] = {};
    short* Pt = VsPt;

#pragma unroll 1
    for (int i = 0; i < 16; i++) {
        const short* kq = smem + 8192 + (i & 1) * 8192;
        __syncthreads();   // KQ(i) resident; V-frags read (i==0); Qs/Pt of i-1 fully consumed
        if (i < 15) {      // prefetch KQ(i+1): in flight across BOTH barriers of this iter
            short* nxt = smem + 8192 + ((i + 1) & 1) * 8192;
            const int t1 = (i + 1) * 64;
#pragma unroll
            for (int p = 0; p < 2; p++) {
                async16(Kbase + t1 * 64 + kOff[p], nxt + dK[p]);
                async16(Qbase + t1 + qOff[p], nxt + dQ[p]);
            }
        }
        // phase A: l = (K*ts*log2e)^T V;  P = exp2(l - mz);  store swizzled Pt
        short8 aK0 = frag64(kq, w * 16 + c, q);
        short8 aK1 = frag64(kq, w * 16 + c, 4 + q);
        const int tr0 = i * 64 + w * 16 + q * 4;
        const float4 mv = *(const float4*)&mzs[tr0];
#pragma unroll
        for (int sf = 0; sf < 8; sf++) {
            f32x4 l = {0.f, 0.f, 0.f, 0.f};
            l = MFMA16(aK0, vb0[sf], l);
            l = MFMA16(aK1, vb1[sf], l);
            const int rr = sf * 16 + c;
            int2v p4;
            p4[0] = cvt_pk_bf16(exp2_hw(l[0] - mv.x), exp2_hw(l[1] - mv.y));
            p4[1] = cvt_pk_bf16(exp2_hw(l[2] - mv.z), exp2_hw(l[3] - mv.w));
            *(int2v*)&Pt[rr * 64 + (((w * 2 + (q >> 1)) ^ (rr & 7)) << 3) + (q & 1) * 4] = p4;
        }
        lds_barrier();     // Pt visible; does NOT drain the KQ(i+1) prefetch
        // phase B: acc += Q * P
        const short* Qs = kq + 4096;
        short8 aQ0 = frag64(Qs, w * 16 + c, q);
        short8 aQ1 = frag64(Qs, w * 16 + c, 4 + q);
        __builtin_amdgcn_s_setprio(1);
#pragma unroll
        for (int sf = 0; sf < 8; sf++) {
            short8 p0 = frag64(Pt, sf * 16 + c, q);
            short8 p1 = frag64(Pt, sf * 16 + c, 4 + q);
            acc[sf] = MFMA16(aQ0, p0, acc[sf]);
            acc[sf] = MFMA16(aQ1, p1, acc[sf]);
        }
        __builtin_amdgcn_s_setprio(0);
    }

#pragma unroll
    for (int sf = 0; sf < 8; sf++) {
#pragma unroll
        for (int r = 0; r < 4; r++) {
            const int d = w * 16 + q * 4 + r;
            out[(size_t)(b * Tv + h * DHv + d) * Dv + s0 + sf * 16 + c] = acc[sf][r];
        }
    }
}

extern "C" void kernel_launch(void* const* d_in, const int* in_sizes, int n_in,
                              void* d_out, int out_size, void* d_ws, size_t ws_size,
                              hipStream_t stream) {
    const float* x    = (const float*)d_in[0];
    const float* Wq   = (const float*)d_in[1];
    const float* bq   = (const float*)d_in[2];
    const float* Wk   = (const float*)d_in[3];
    const float* bk   = (const float*)d_in[4];
    const float* Wv   = (const float*)d_in[5];
    const float* bv   = (const float*)d_in[6];
    const float* temp = (const float*)d_in[7];
    float* out = (float*)d_out;

    char* ws = (char*)d_ws;
    short* xb = (short*)(ws);                       // [0, 8M)
    short* Wt = (short*)(ws + ((size_t)8 << 20));   // [8M, 14M)
    short* Qb = (short*)(ws + ((size_t)14 << 20));  // [14M, 22M)
    short* Kt = (short*)(ws + ((size_t)22 << 20));  // [22M, 30M)
    short* Vt = (short*)(ws + ((size_t)30 << 20));  // [30M, 38M)
    float* mzbuf = (float*)(ws + ((size_t)38 << 20));

    cast_x<<<4096, 256, 0, stream>>>(x, xb);
    w_cast_t<<<dim3(16, 16, 3), 256, 0, stream>>>(Wq, Wk, Wv, Wt);
    qkv_mfma<<<dim3(4, 16, 3), 512, 0, stream>>>(xb, Wt, bq, bk, bv, temp, Qb, Kt, Vt);
    attn_stats<<<dim3(16, 16, 4), 256, 0, stream>>>(Kt, Vt, mzbuf);
    attn_out<<<dim3(8, 16, 4), 256, 0, stream>>>(Qb, Kt, Vt, mzbuf, out);
}

// Round 7
// 154.116 us; speedup vs baseline: 1.2665x; 1.0425x over previous
//
#include <hip/hip_runtime.h>
#include <math.h>

#define Bv 4
#define Tv 1024
#define Dv 1024
#define Hv 16
#define DHv 64
#define L2E 1.4426950408889634f

typedef __attribute__((ext_vector_type(8))) short short8;
typedef __attribute__((ext_vector_type(4))) short short4v;
typedef __attribute__((ext_vector_type(4))) float f32x4;
typedef __attribute__((ext_vector_type(2))) int int2v;

#define MFMA16(a, b, c) __builtin_amdgcn_mfma_f32_16x16x32_bf16((a), (b), (c), 0, 0, 0)

__device__ __forceinline__ short f2bf(float f) {
    union { float f; unsigned u; } v; v.f = f;
    unsigned r = v.u + 0x7FFFu + ((v.u >> 16) & 1u);
    return (short)(r >> 16);
}

// hardware exp2/log2 via compiler-known builtins (proper TRANS-hazard modeling)
__device__ __forceinline__ float exp2_hw(float x) {
#if __has_builtin(__builtin_amdgcn_exp2f)
    return __builtin_amdgcn_exp2f(x);
#else
    return exp2f(x);
#endif
}
__device__ __forceinline__ float log2_hw(float x) {
#if __has_builtin(__builtin_amdgcn_logf)
    return __builtin_amdgcn_logf(x);
#else
    return log2f(x);
#endif
}

// packed bf16 convert (RTNE, same rounding as f2bf). Non-TRANS VOP3: no hazard class.
__device__ __forceinline__ int cvt_pk_bf16(float lo, float hi) {
    int r; asm("v_cvt_pk_bf16_f32 %0, %1, %2" : "=v"(r) : "v"(lo), "v"(hi)); return r;
}

__device__ __forceinline__ void async16(const void* g, void* l) {
    __builtin_amdgcn_global_load_lds(
        (const __attribute__((address_space(1))) void*)g,
        (__attribute__((address_space(3))) void*)l, 16, 0, 0);
}

// Fragment read from a 64-short-wide tile stored with chunk-XOR swizzle
// (chunk cw of row r lives at slot cw ^ (r&7)). 2-way bank aliasing only.
__device__ __forceinline__ short8 frag64(const short* buf, int r, int cw) {
    return *(const short8*)&buf[r * 64 + ((cw ^ (r & 7)) << 3)];
}

// 32-short-wide (BK=32) variant: 4 chunks per row, slot = (cw ^ (r>>1)) & 3.
__device__ __forceinline__ short8 frag32(const short* buf, int r, int cw) {
    return *(const short8*)&buf[r * 32 + (((cw ^ (r >> 1)) & 3) << 3)];
}

// ---------------- cast x -> packed bf16 K-panels: xp[kb][t][32] ----------------
// Panel layout makes every qkv staging wave-instruction a contiguous 1 KB read.
__global__ __launch_bounds__(256) void cast_x(const float* __restrict__ x, short* __restrict__ xp) {
    const int idx = blockIdx.x * 256 + threadIdx.x;   // 2048 blocks x 256 thr, 8 elems each
    const int t = idx >> 7, j = idx & 127;            // token, k-chunk-of-8
    const float* src = x + (size_t)t * 1024 + j * 8;
    float4 f0 = ((const float4*)src)[0], f1 = ((const float4*)src)[1];
    short8 o;
    o[0] = f2bf(f0.x); o[1] = f2bf(f0.y); o[2] = f2bf(f0.z); o[3] = f2bf(f0.w);
    o[4] = f2bf(f1.x); o[5] = f2bf(f1.y); o[6] = f2bf(f1.z); o[7] = f2bf(f1.w);
    *(short8*)&xp[(j >> 2) * 131072 + t * 32 + (j & 3) * 8] = o;
}

// ---------------- cast + transpose W -> packed panels Wp[z][kb][n][32] ----------------
__global__ __launch_bounds__(256) void w_cast_t(
    const float* __restrict__ Wq, const float* __restrict__ Wk, const float* __restrict__ Wv,
    short* __restrict__ Wt)
{
    const float* W = (blockIdx.z == 0) ? Wq : (blockIdx.z == 1) ? Wk : Wv;
    short* Wto = Wt + (size_t)blockIdx.z * 1048576;
    __shared__ short Tl[64 * 72];
    const int k0 = blockIdx.y * 64, n0 = blockIdx.x * 64;
    const int tid = threadIdx.x;
    {
        const int r = tid >> 2, c16 = (tid & 3) * 16;
        const float* src = W + (size_t)(k0 + r) * Dv + n0 + c16;
        float4 f0 = ((const float4*)src)[0], f1 = ((const float4*)src)[1];
        float4 f2 = ((const float4*)src)[2], f3 = ((const float4*)src)[3];
        short8 s0, s1;
        s0[0] = f2bf(f0.x); s0[1] = f2bf(f0.y); s0[2] = f2bf(f0.z); s0[3] = f2bf(f0.w);
        s0[4] = f2bf(f1.x); s0[5] = f2bf(f1.y); s0[6] = f2bf(f1.z); s0[7] = f2bf(f1.w);
        s1[0] = f2bf(f2.x); s1[1] = f2bf(f2.y); s1[2] = f2bf(f2.z); s1[3] = f2bf(f2.w);
        s1[4] = f2bf(f3.x); s1[5] = f2bf(f3.y); s1[6] = f2bf(f3.z); s1[7] = f2bf(f3.w);
        *(short8*)&Tl[r * 72 + c16] = s0;
        *(short8*)&Tl[r * 72 + c16 + 8] = s1;
    }
    __syncthreads();
#pragma unroll
    for (int p = 0; p < 2; p++) {
        const int n = p * 32 + (tid >> 3), j8 = (tid & 7) * 8;
        short8 o;
#pragma unroll
        for (int jj = 0; jj < 8; jj++) o[jj] = Tl[(j8 + jj) * 72 + n];
        const int kk = k0 + j8;
        *(short8*)&Wto[(kk >> 5) * 32768 + (size_t)(n0 + n) * 32 + (kk & 31)] = o;
    }
}

// ---------------- QKV projection: merged-z 128x128 tile, BK=32, 3-deep pipeline ----------------
// One block computes Q, K, V for the same 128 tokens x 128 output features:
// x-panel staged ONCE feeds 3 W-panels; 24 MFMA per wave per K-step; 256 blocks = 1/CU.
// LDS (shorts): A[s] @ s*4096 (s=0..2); B[s][z] @ 12288 + (s*3+z)*4096. 96 KiB.
__global__ __launch_bounds__(512, 2) void qkv_mfma(
    const short* __restrict__ xp, const short* __restrict__ Wp,
    const float* __restrict__ bq, const float* __restrict__ bk, const float* __restrict__ bv,
    const float* __restrict__ temp,
    short* __restrict__ Qo, short* __restrict__ Kt, short* __restrict__ Vt)
{
    __shared__ short smem[49152];

    const int tid = threadIdx.x;
    const int lane = tid & 63, w = tid >> 6;
    const int q = lane >> 4, c = lane & 15;
    const int wr = w >> 2, wc = w & 3;           // 2x4 wave grid: 64 rows x 32 cols each
    const int n0 = blockIdx.x * 128, tm0 = blockIdx.y * 128;

    // staging offsets: contiguous panel + per-row chunk pre-swizzle for frag32
    const int sr = tid >> 2, scs = tid & 3, scg = (scs ^ (sr >> 1)) & 3;
    const int aOff = (tm0 + sr) * 32 + scg * 8;
    const int bOff = (n0 + sr) * 32 + scg * 8;
    const int dOff = tid * 8;

    f32x4 acc[3][4][2] = {};

    auto stage = [&](int s, int kb) {
        async16(xp + kb * 131072 + aOff, smem + s * 4096 + dOff);
#pragma unroll
        for (int z = 0; z < 3; z++)
            async16(Wp + z * 1048576 + kb * 32768 + bOff,
                    smem + 12288 + (s * 3 + z) * 4096 + dOff);
    };
    auto compute = [&](int s) {
        const short* Ac = smem + s * 4096;
        short8 af[4];
#pragma unroll
        for (int m = 0; m < 4; m++) af[m] = frag32(Ac, wr * 64 + m * 16 + c, q);
        __builtin_amdgcn_s_setprio(1);
#pragma unroll
        for (int z = 0; z < 3; z++) {
            const short* Bc = smem + 12288 + (s * 3 + z) * 4096;
            short8 b0 = frag32(Bc, wc * 32 + c, q);
            short8 b1 = frag32(Bc, wc * 32 + 16 + c, q);
#pragma unroll
            for (int m = 0; m < 4; m++) {
                acc[z][m][0] = MFMA16(af[m], b0, acc[z][m][0]);
                acc[z][m][1] = MFMA16(af[m], b1, acc[z][m][1]);
            }
        }
        __builtin_amdgcn_s_setprio(0);
    };

    stage(0, 0); stage(1, 1);                    // 8 loads in flight

    int sC = 0, sS = 2;
#pragma unroll 1
    for (int i = 0; i < 30; i++) {
        asm volatile("s_waitcnt vmcnt(4)" ::: "memory");   // tile i resident; i+1 in flight
        __builtin_amdgcn_s_barrier();
        __builtin_amdgcn_sched_barrier(0);
        stage(sS, i + 2);
        compute(sC);
        sC = (sC == 2) ? 0 : sC + 1;
        sS = (sS == 2) ? 0 : sS + 1;
    }
    asm volatile("s_waitcnt vmcnt(4)" ::: "memory");
    __builtin_amdgcn_s_barrier();
    __builtin_amdgcn_sched_barrier(0);
    compute(sC);
    sC = (sC == 2) ? 0 : sC + 1;
    asm volatile("s_waitcnt vmcnt(0)" ::: "memory");
    __builtin_amdgcn_s_barrier();
    __builtin_amdgcn_sched_barrier(0);
    compute(sC);

    // ---- epilogue ----
    // Q: natural layout, direct stores (no LDS -> safe before any barrier)
#pragma unroll
    for (int jj = 0; jj < 2; jj++) {
        const int col = n0 + wc * 32 + jj * 16 + c;
        const float bb = bq[col];
#pragma unroll
        for (int m = 0; m < 4; m++)
#pragma unroll
            for (int rr = 0; rr < 4; rr++) {
                const int row = tm0 + wr * 64 + m * 16 + q * 4 + rr;
                Qo[(size_t)row * Dv + col] = f2bf(acc[0][m][jj][rr] + bb);
            }
    }
    // K (scaled by temp[h]*log2e) and V: per-head transposed via LDS T[n 128][tok], stride 136
    const int hb = tm0 >> 6;                     // global head-block (b*16+h), 2 per tile
#pragma unroll
    for (int z = 1; z < 3; z++) {
        const float* bias = (z == 1) ? bk : bv;
        short* dst = (z == 1) ? Kt : Vt;
        float scl = 1.f;
        if (z == 1) scl = temp[(hb + wr) & 15] * L2E;   // wave's 64 rows = one head
        __syncthreads();                         // T-region free (K-loop / prev scatter done)
        short* T = smem;
#pragma unroll
        for (int jj = 0; jj < 2; jj++) {
            const int nl = wc * 32 + jj * 16 + c;
            const float bb = bias[n0 + nl];
#pragma unroll
            for (int m = 0; m < 4; m++) {
                int2v pk;
                pk[0] = cvt_pk_bf16((acc[z][m][jj][0] + bb) * scl, (acc[z][m][jj][1] + bb) * scl);
                pk[1] = cvt_pk_bf16((acc[z][m][jj][2] + bb) * scl, (acc[z][m][jj][3] + bb) * scl);
                *(int2v*)&T[nl * 136 + wr * 64 + m * 16 + q * 4] = pk;
            }
        }
        __syncthreads();
#pragma unroll
        for (int p = 0; p < 4; p++) {
            const int idx = p * 512 + tid;
            const int n = idx >> 4, k2 = idx & 15;
            short8 v = *(const short8*)&T[n * 136 + k2 * 8];
            const size_t addr = (size_t)(hb + (k2 >> 3)) * 65536 +
                                (size_t)(n0 + n) * 64 + (k2 & 7) * 8;
            *(short8*)&dst[addr] = v;
        }
    }
}

// ---------------- attention stats: mz[t] = log2( sum_s exp2(l[t,s]) ) ----------------
__global__ __launch_bounds__(256, 4) void attn_stats(
    const short* __restrict__ Kt, const short* __restrict__ Vt,
    float* __restrict__ mzOut)
{
    // XCD remap: the 16 t-blocks of one (b,h) share V -> same id mod 8 (same XCD L2).
    const int L = blockIdx.x + 16 * (blockIdx.y + 16 * blockIdx.z);
    const int bh = (L & 7) + 8 * (L >> 7);
    const int t0 = ((L >> 3) & 15) * 64;
    __shared__ short Ks[64 * 64];
    __shared__ short Vs[2][128 * 64];
    const int tid = threadIdx.x;
    const int lane = tid & 63, w = tid >> 6;
    const int q = lane >> 4, c = lane & 15;
    const short* Kbase = Kt + (size_t)bh * 65536;
    const short* Vbase = Vt + (size_t)bh * 65536;

    int vOff[4], vDst[4];
#pragma unroll
    for (int p = 0; p < 4; p++) {
        const int idx = p * 256 + tid;
        const int r = idx >> 3, cs = idx & 7, cg = cs ^ (r & 7);
        vOff[p] = r * 64 + cg * 8;
        vDst[p] = idx * 8;
    }
#pragma unroll
    for (int p = 0; p < 2; p++) {
        const int idx = p * 256 + tid;
        const int r = idx >> 3, cs = idx & 7, cg = cs ^ (r & 7);
        async16(Kbase + (size_t)(t0 + r) * 64 + cg * 8, Ks + idx * 8);
    }
#pragma unroll
    for (int p = 0; p < 4; p++) async16(Vbase + vOff[p], &Vs[0][0] + vDst[p]);

    float z_run[4] = {0.f, 0.f, 0.f, 0.f};

    short8 aK0, aK1;
#pragma unroll 1
    for (int i = 0; i < 8; i++) {
        __syncthreads();                       // V(i) resident everywhere
        if (i < 7) {                           // prefetch V(i+1); drains at NEXT iter top
            const short* src = Vbase + (i + 1) * 8192;
#pragma unroll
            for (int p = 0; p < 4; p++) async16(src + vOff[p], &Vs[(i + 1) & 1][0] + vDst[p]);
        }
        if (i == 0) {
            aK0 = frag64(Ks, w * 16 + c, q);
            aK1 = frag64(Ks, w * 16 + c, 4 + q);
        }
        const short* Vc = &Vs[i & 1][0];
        __builtin_amdgcn_s_setprio(1);
#pragma unroll
        for (int sf = 0; sf < 8; sf++) {
            short8 b0 = frag64(Vc, sf * 16 + c, q);
            short8 b1 = frag64(Vc, sf * 16 + c, 4 + q);
            f32x4 l = {0.f, 0.f, 0.f, 0.f};
            l = MFMA16(aK0, b0, l);
            l = MFMA16(aK1, b1, l);
#pragma unroll
            for (int r = 0; r < 4; r++) z_run[r] += exp2_hw(l[r]);
        }
        __builtin_amdgcn_s_setprio(0);
    }
#pragma unroll
    for (int mask = 1; mask <= 8; mask <<= 1) {
#pragma unroll
        for (int r = 0; r < 4; r++) z_run[r] += __shfl_xor(z_run[r], mask, 64);
    }
    if (c == 0) {
#pragma unroll
        for (int r = 0; r < 4; r++) {
            const int t = t0 + w * 16 + q * 4 + r;
            mzOut[(size_t)bh * Tv + t] = log2_hw(z_run[r]);
        }
    }
}

// ---------------- attention output: P = exp2(l - mz), pipelined K/Q, V in regs ----------------
__global__ __launch_bounds__(256, 2) void attn_out(
    const short* __restrict__ Qb, const short* __restrict__ Kt, const short* __restrict__ Vt,
    const float* __restrict__ mzIn, float* __restrict__ out)
{
    // XCD remap: 8 s-blocks of one (b,h) share K/Q -> same id mod 8.
    const int L = blockIdx.x + 8 * (blockIdx.y + 16 * blockIdx.z);
    const int bh = (L & 7) + 8 * (L >> 6);
    const int s0 = ((L >> 3) & 7) * 128;
    const int b = bh >> 4, h = bh & 15;

    __shared__ short smem[26624];
    short* VsPt = smem;
    float* mzs = (float*)(smem + 24576);

    const int tid = threadIdx.x;
    const int lane = tid & 63, w = tid >> 6;
    const int q = lane >> 4, c = lane & 15;
    const short* Vbase = Vt + (size_t)bh * 65536;
    const short* Kbase = Kt + (size_t)bh * 65536;
    const short* Qbase = Qb + (size_t)(b * Tv + h * DHv) * Dv;

    int kOff[2], qOff[2], dK[2], dQ[2];
#pragma unroll
    for (int p = 0; p < 2; p++) {
        const int idx = p * 256 + tid;
        const int r = idx >> 3, cs = idx & 7, cg = cs ^ (r & 7);
        kOff[p] = r * 64 + cg * 8;
        qOff[p] = r * 1024 + cg * 8;
        dK[p] = idx * 8;
        dQ[p] = 4096 + idx * 8;
    }

#pragma unroll
    for (int p = 0; p < 4; p++) {
        const int idx = p * 256 + tid;
        const int r = idx >> 3, cs = idx & 7, cg = cs ^ (r & 7);
        async16(Vbase + (size_t)(s0 + r) * 64 + cg * 8, VsPt + idx * 8);
    }
    async16(mzIn + (size_t)bh * Tv + tid * 4, (short*)mzs + tid * 8);
#pragma unroll
    for (int p = 0; p < 2; p++) {
        async16(Kbase + kOff[p], smem + 8192 + dK[p]);
        async16(Qbase + qOff[p], smem + 8192 + dQ[p]);
    }
    __syncthreads();

    short8 vb0[8], vb1[8];
#pragma unroll
    for (int sf = 0; sf < 8; sf++) {
        vb0[sf] = frag64(VsPt, sf * 16 + c, q);
        vb1[sf] = frag64(VsPt, sf * 16 + c, 4 + q);
    }

    f32x4 acc[8] = {};
    short* Pt = VsPt;

#pragma unroll 1
    for (int i = 0; i < 16; i++) {
        const short* kq = smem + 8192 + (i & 1) * 8192;
        __syncthreads();
        if (i < 15) {
            short* nxt = smem + 8192 + ((i + 1) & 1) * 8192;
            const int t1 = (i + 1) * 64;
#pragma unroll
            for (int p = 0; p < 2; p++) {
                async16(Kbase + t1 * 64 + kOff[p], nxt + dK[p]);
                async16(Qbase + t1 + qOff[p], nxt + dQ[p]);
            }
        }
        short8 aK0 = frag64(kq, w * 16 + c, q);
        short8 aK1 = frag64(kq, w * 16 + c, 4 + q);
        const int tr0 = i * 64 + w * 16 + q * 4;
        const float4 mv = *(const float4*)&mzs[tr0];
#pragma unroll
        for (int sf = 0; sf < 8; sf++) {
            f32x4 l = {0.f, 0.f, 0.f, 0.f};
            l = MFMA16(aK0, vb0[sf], l);
            l = MFMA16(aK1, vb1[sf], l);
            const int rr = sf * 16 + c;
            int2v p4;
            p4[0] = cvt_pk_bf16(exp2_hw(l[0] - mv.x), exp2_hw(l[1] - mv.y));
            p4[1] = cvt_pk_bf16(exp2_hw(l[2] - mv.z), exp2_hw(l[3] - mv.w));
            *(int2v*)&Pt[rr * 64 + (((w * 2 + (q >> 1)) ^ (rr & 7)) << 3) + (q & 1) * 4] = p4;
        }
        asm volatile("s_waitcnt lgkmcnt(0)" ::: "memory");
        __builtin_amdgcn_sched_barrier(0);
        __builtin_amdgcn_s_barrier();
        __builtin_amdgcn_sched_barrier(0);
        const short* Qs = kq + 4096;
        short8 aQ0 = frag64(Qs, w * 16 + c, q);
        short8 aQ1 = frag64(Qs, w * 16 + c, 4 + q);
        __builtin_amdgcn_s_setprio(1);
#pragma unroll
        for (int sf = 0; sf < 8; sf++) {
            short8 p0 = frag64(Pt, sf * 16 + c, q);
            short8 p1 = frag64(Pt, sf * 16 + c, 4 + q);
            acc[sf] = MFMA16(aQ0, p0, acc[sf]);
            acc[sf] = MFMA16(aQ1, p1, acc[sf]);
        }
        __builtin_amdgcn_s_setprio(0);
    }

#pragma unroll
    for (int sf = 0; sf < 8; sf++) {
#pragma unroll
        for (int r = 0; r < 4; r++) {
            const int d = w * 16 + q * 4 + r;
            out[(size_t)(b * Tv + h * DHv + d) * Dv + s0 + sf * 16 + c] = acc[sf][r];
        }
    }
}

extern "C" void kernel_launch(void* const* d_in, const int* in_sizes, int n_in,
                              void* d_out, int out_size, void* d_ws, size_t ws_size,
                              hipStream_t stream) {
    const float* x    = (const float*)d_in[0];
    const float* Wq   = (const float*)d_in[1];
    const float* bq   = (const float*)d_in[2];
    const float* Wk   = (const float*)d_in[3];
    const float* bk   = (const float*)d_in[4];
    const float* Wv   = (const float*)d_in[5];
    const float* bv   = (const float*)d_in[6];
    const float* temp = (const float*)d_in[7];
    float* out = (float*)d_out;

    char* ws = (char*)d_ws;
    short* xp = (short*)(ws);                       // [0, 8M)   packed x panels
    short* Wp = (short*)(ws + ((size_t)8 << 20));   // [8M, 14M) packed W panels (3z)
    short* Qb = (short*)(ws + ((size_t)14 << 20));  // [14M, 22M)
    short* Kt = (short*)(ws + ((size_t)22 << 20));  // [22M, 30M)
    short* Vt = (short*)(ws + ((size_t)30 << 20));  // [30M, 38M)
    float* mzbuf = (float*)(ws + ((size_t)38 << 20));

    cast_x<<<2048, 256, 0, stream>>>(x, xp);
    w_cast_t<<<dim3(16, 16, 3), 256, 0, stream>>>(Wq, Wk, Wv, Wp);
    qkv_mfma<<<dim3(8, 32), 512, 0, stream>>>(xp, Wp, bq, bk, bv, temp, Qb, Kt, Vt);
    attn_stats<<<dim3(16, 16, 4), 256, 0, stream>>>(Kt, Vt, mzbuf);
    attn_out<<<dim3(8, 16, 4), 256, 0, stream>>>(Qb, Kt, Vt, mzbuf, out);
}